// Round 8
// baseline (364.385 us; speedup 1.0000x reference)
//
#include <hip/hip_runtime.h>
#include <hip/hip_bf16.h>

#define C_ 256
#define G_ 4

typedef __attribute__((ext_vector_type(8))) short bf16x8;
typedef __attribute__((ext_vector_type(4))) float f32x4;

static __device__ __forceinline__ unsigned short f2bf(float x) {
    __hip_bfloat16 h = __float2bfloat16(x);
    return *(unsigned short*)&h;
}
static __device__ __forceinline__ float bf2f(unsigned short u) {
    return __uint_as_float((unsigned)u << 16);
}
static __device__ __forceinline__ float4 bf4(ushort4 u) {
    float4 r;
    r.x = bf2f(u.x);
    r.y = bf2f(u.y);
    r.z = bf2f(u.z);
    r.w = bf2f(u.w);
    return r;
}

// total bilinear weight that source row y receives across all Hf output rows;
// mirrors the store interp exactly (trunc coords, y1 = min(y0+1, Hr-1) clamp).
static __device__ __forceinline__ float upw(int y, int Hr, int Hf, float sys) {
    float inv = 1.f / sys;
    int lo = max(0, (int)((y - 1) * inv) - 1);
    int hi = min(Hf - 1, (int)((y + 1) * inv) + 1);
    float w = 0.f;
    for (int o = lo; o <= hi; o++) {
        float sy = o * sys;
        int y0 = (int)sy;
        float fy = sy - y0;
        int y1 = min(y0 + 1, Hr - 1);
        if (y0 == y) w += 1.f - fy;
        if (y1 == y) w += fy;
    }
    return w;
}

// ---------------------------------------------------------------- prep ----
__global__ void k_prep(const float* __restrict__ off_w, const float* __restrict__ dwh,
                       const float* __restrict__ dwm, const float* __restrict__ dwl,
                       unsigned short* __restrict__ wmf, float* __restrict__ dwt,
                       float* __restrict__ zeros, float* __restrict__ rep) {
    int i = blockIdx.x * 256 + threadIdx.x;
    const int NWM = 4 * 32 * 576;
    if (i < NWM) {
        int g = i / (32 * 576), rem = i % (32 * 576);
        int ol = rem / 576, kk = rem % 576;
        int tap = kk / 64, ic = kk % 64;
        float v = (ol < 27) ? off_w[((size_t)((g * 27 + ol) * 64 + ic)) * 9 + tap] : 0.f;
        wmf[i] = f2bf(v);
    }
    int j = i - NWM;
    if (j >= 0 && j < 3 * 2304) {
        int which = j / 2304, rem = j % 2304;
        int t = rem / 256, c = rem % 256;
        const float* src = (which == 0) ? dwh : (which == 1) ? dwm : dwl;
        dwt[j] = src[c * 9 + t];
    }
    int z = i - NWM - 3 * 2304;
    if (z >= 0 && z < 896) zeros[z] = 0.f;
    int z2 = z - 896;
    if (z2 >= 0 && z2 < 4 * 7168) rep[z2] = 0.f;
}

// ------------------------------------------------- batched transpose (3 srcs) ----
struct TrP {
    const float* x[3];
    unsigned short* xtb[3];
    int H[3];
    int W[3];
    int wtc[3];
    int blk[4];
};

__global__ __launch_bounds__(256) void k_transpose_b(TrP P) {
    __shared__ float tile[32][33];
    int b = blockIdx.x;
    int f = (b >= P.blk[1]) + (b >= P.blk[2]);
    int l = b - P.blk[f];
    int H = P.H[f], W = P.W[f], wtc = P.wtc[f];
    int nh = l / wtc, wtile = l - nh * wtc;
    int n = nh / H, h = nh % H;
    int w0 = wtile * 32, c0 = blockIdx.y * 32;
    const float* x = P.x[f];
    unsigned short* xtb = P.xtb[f];
    int tid = threadIdx.x;
    int i = tid / 32, j = tid % 32;
#pragma unroll
    for (int r = 0; r < 4; r++) {
        int c = c0 + i + r * 8;
        int w = w0 + j;
        tile[i + r * 8][j] = (w < W) ? x[((size_t)(n * C_ + c) * H + h) * W + w] : 0.f;
    }
    __syncthreads();
    int wj = tid >> 4, ci2 = (tid & 15) * 2;
#pragma unroll
    for (int r = 0; r < 2; r++) {
        int w = w0 + wj + r * 16;
        if (w < W) {
            ushort2 o;
            o.x = f2bf(tile[ci2][wj + r * 16]);
            o.y = f2bf(tile[ci2 + 1][wj + r * 16]);
            *(ushort2*)(xtb + ((size_t)(n * H + h) * W + w) * C_ + c0 + ci2) = o;
        }
    }
}

// ------ fused depthwise+SiLU + grouped offset/mask conv (per LDS class) ----
// Stages the xtb halo-of-halo (zero-padded), computes dw+scale+bias+SiLU per
// patch pixel into bf16 LDS (bit-identical to the old dwb), then the proven
// MFMA phase. Eliminates the dwb global round-trip entirely.
struct OdP {
    const unsigned short* xtb[5];
    float* om[5];
    const float* wdt[5];
    const float* sc[5];
    const float* bi[5];
    int Hs[5], Ws[5], Wo[5], HoWo[5];
    int ss[5], ths[5], tws[5];
    int SR[5], SC[5], Msc[5], XC[5], Mxc[5];
    int nz[5], Mnz[5];
    int blk[6];
};

template <int XPX, int PPX>
__global__ __launch_bounds__(256) void k_offdw_b(OdP P,
                                                 const unsigned short* __restrict__ wmf) {
    __shared__ __align__(16) unsigned short xpatch[XPX * 72];
    __shared__ __align__(16) unsigned short patch[PPX * 72];
    float* omv = (float*)xpatch;  // overlay: xpatch dead after dw phase

    int tid = threadIdx.x;
    int wv = tid >> 6, lane = tid & 63;
    int n16 = lane & 15, q = lane >> 4;
    int b = blockIdx.x;
    int f = (b >= P.blk[1]) + (b >= P.blk[2]) + (b >= P.blk[3]) + (b >= P.blk[4]);
    int l = b - P.blk[f];
    int n = (l >> 2) & 3, g = l & 3;
    int tile = l >> 4;
    int nz = P.nz[f];
    int ty = (tile * P.Mnz[f]) >> 16;
    int tz = tile - ty * nz;
    int ss = P.ss[f], ths = P.ths[f], tws = P.tws[f];
    int TW = 1 << tws;
    int SR = P.SR[f], SC = P.SC[f], Msc = P.Msc[f];
    int XC = P.XC[f], Mxc = P.Mxc[f];
    int XNV = (SR + 2) * XC;
    int NV = SR * SC;
    int Hs = P.Hs[f], Ws = P.Ws[f], Wo = P.Wo[f], HoWo = P.HoWo[f];
    int ho0 = ty << ths, wo0 = tz << tws;
    int hs0 = (ho0 << ss) - 1, ws0 = (wo0 << ss) - 1;
    const unsigned short* xtb = P.xtb[f] + (size_t)n * Hs * Ws * C_ + g * 64;
    float* om = P.om[f];
    const float* wdt = P.wdt[f] + g * 64;
    const float* scp = P.sc[f] + g * 64;
    const float* bip = P.bi[f] + g * 64;

    // stage xtb halo (origin (hs0-1, ws0-1)), zero OOB
    for (int idx = tid; idx < XNV * 8; idx += 256) {
        int pp = idx >> 3;
        int c8 = (idx & 7) << 3;
        int pq = (pp * Mxc) >> 16;
        int hh = hs0 - 1 + pq, ww = ws0 - 1 + (pp - pq * XC);
        uint4 v = {0u, 0u, 0u, 0u};
        if (hh >= 0 && hh < Hs && ww >= 0 && ww < Ws)
            v = *(const uint4*)(xtb + ((size_t)hh * Ws + ww) * C_ + c8);
        *(uint4*)(xpatch + pp * 72 + c8) = v;
    }
    __syncthreads();

    // dw conv + scale/bias + SiLU -> bf16 patch (zero for out-of-image pixels)
    for (int idx = tid; idx < NV * 8; idx += 256) {
        int pp = idx >> 3;
        int c8 = (idx & 7) << 3;
        int pq = (pp * Msc) >> 16;
        int pr = pq, pc = pp - pq * SC;
        int hh = hs0 + pr, ww = ws0 + pc;
        uint4 ov = {0u, 0u, 0u, 0u};
        if (hh >= 0 && hh < Hs && ww >= 0 && ww < Ws) {
            float4 accA = {0.f, 0.f, 0.f, 0.f}, accB = {0.f, 0.f, 0.f, 0.f};
#pragma unroll
            for (int t = 0; t < 9; t++) {
                int xr = pr + t / 3, xc = pc + t % 3;
                bf16x8 xv = *(const bf16x8*)(xpatch + (xr * XC + xc) * 72 + c8);
                float4 wa = *(const float4*)(wdt + t * 256 + c8);
                float4 wb = *(const float4*)(wdt + t * 256 + c8 + 4);
                accA.x += wa.x * bf2f((unsigned short)xv[0]);
                accA.y += wa.y * bf2f((unsigned short)xv[1]);
                accA.z += wa.z * bf2f((unsigned short)xv[2]);
                accA.w += wa.w * bf2f((unsigned short)xv[3]);
                accB.x += wb.x * bf2f((unsigned short)xv[4]);
                accB.y += wb.y * bf2f((unsigned short)xv[5]);
                accB.z += wb.z * bf2f((unsigned short)xv[6]);
                accB.w += wb.w * bf2f((unsigned short)xv[7]);
            }
            float4 sa = *(const float4*)(scp + c8), sb = *(const float4*)(scp + c8 + 4);
            float4 ba = *(const float4*)(bip + c8), bb = *(const float4*)(bip + c8 + 4);
            float y0 = accA.x * sa.x + ba.x, y1 = accA.y * sa.y + ba.y;
            float y2 = accA.z * sa.z + ba.z, y3 = accA.w * sa.w + ba.w;
            float y4 = accB.x * sb.x + bb.x, y5 = accB.y * sb.y + bb.y;
            float y6 = accB.z * sb.z + bb.z, y7 = accB.w * sb.w + bb.w;
            y0 = y0 / (1.f + __expf(-y0));
            y1 = y1 / (1.f + __expf(-y1));
            y2 = y2 / (1.f + __expf(-y2));
            y3 = y3 / (1.f + __expf(-y3));
            y4 = y4 / (1.f + __expf(-y4));
            y5 = y5 / (1.f + __expf(-y5));
            y6 = y6 / (1.f + __expf(-y6));
            y7 = y7 / (1.f + __expf(-y7));
            ov.x = (unsigned)f2bf(y0) | ((unsigned)f2bf(y1) << 16);
            ov.y = (unsigned)f2bf(y2) | ((unsigned)f2bf(y3) << 16);
            ov.z = (unsigned)f2bf(y4) | ((unsigned)f2bf(y5) << 16);
            ov.w = (unsigned)f2bf(y6) | ((unsigned)f2bf(y7) << 16);
        }
        *(uint4*)(patch + pp * 72 + c8) = ov;
    }
    __syncthreads();

    int bchan = q << 3;
    const unsigned short* wg = wmf + (size_t)g * 32 * 576;
    int TP = 1 << (ths + tws);
    int sc1 = SC, sc2 = SC * 2;

    if (TP == 64) {
        int p = wv * 16 + n16;
        int pr = p >> tws, pc = p & (TW - 1);
        int pixbase = (pr << ss) * SC + (pc << ss);
        f32x4 a0 = {0.f, 0.f, 0.f, 0.f}, a1 = {0.f, 0.f, 0.f, 0.f};
#pragma unroll
        for (int kk = 0; kk < 18; kk++) {
            int tap = kk >> 1;
            int ic0 = (kk & 1) << 5;
            int tr = tap / 3, tc = tap % 3;
            int ppix = pixbase + (tr == 0 ? 0 : (tr == 1 ? sc1 : sc2)) + tc;
            bf16x8 bbv = *(const bf16x8*)(patch + ppix * 72 + ic0 + bchan);
            bf16x8 wa0 = *(const bf16x8*)(wg + (size_t)n16 * 576 + kk * 32 + bchan);
            bf16x8 wa1 = *(const bf16x8*)(wg + (size_t)(16 + n16) * 576 + kk * 32 + bchan);
            a0 = __builtin_amdgcn_mfma_f32_16x16x32_bf16(wa0, bbv, a0, 0, 0, 0);
            a1 = __builtin_amdgcn_mfma_f32_16x16x32_bf16(wa1, bbv, a1, 0, 0, 0);
        }
        __syncthreads();
#pragma unroll
        for (int r = 0; r < 4; r++) {
            int ol0 = q * 4 + r;
            omv[p * 28 + ol0] = a0[r];
            int ol1 = 16 + q * 4 + r;
            if (ol1 < 28) omv[p * 28 + ol1] = a1[r];
        }
    } else {
        int NT = TP >> 3;
        int t = wv;
        bool active = t < NT;
        int ntile = t >> 1, mtile = t & 1;
        int p = ntile * 16 + n16;
        int pr = p >> tws, pc = p & (TW - 1);
        int pixbase = (pr << ss) * SC + (pc << ss);
        f32x4 acc = {0.f, 0.f, 0.f, 0.f};
        if (active) {
#pragma unroll
            for (int kk = 0; kk < 18; kk++) {
                int tap = kk >> 1;
                int ic0 = (kk & 1) << 5;
                int tr = tap / 3, tc = tap % 3;
                int ppix = pixbase + (tr == 0 ? 0 : (tr == 1 ? sc1 : sc2)) + tc;
                bf16x8 bbv = *(const bf16x8*)(patch + ppix * 72 + ic0 + bchan);
                bf16x8 wa = *(const bf16x8*)(wg + (size_t)(mtile * 16 + n16) * 576 +
                                             kk * 32 + bchan);
                acc = __builtin_amdgcn_mfma_f32_16x16x32_bf16(wa, bbv, acc, 0, 0, 0);
            }
        }
        __syncthreads();
        if (active) {
#pragma unroll
            for (int r = 0; r < 4; r++) {
                int ol = mtile * 16 + q * 4 + r;
                if (ol < 28) omv[p * 28 + ol] = acc[r];
            }
        }
    }
    __syncthreads();

    float* omg = om + ((size_t)(g * 4 + n)) * HoWo * 28;
    for (int idx = tid; idx < TP * 7; idx += 256) {
        int p = (idx * 9363) >> 16;
        int c4 = idx - p * 7;
        int ho = ho0 + (p >> tws), wo = wo0 + (p & (TW - 1));
        int pixn = ho * Wo + wo;
        *(float4*)(omg + (size_t)pixn * 28 + c4 * 4) = *(float4*)(omv + p * 28 + c4 * 4);
    }
}

// -------------- batched DCNv3 sample (7 feats) + per-channel weighted sums ----
struct SmP {
    const unsigned short* xtb[7];
    const float* om[7];
    unsigned short* raw[7];
    float* stats[7];
    float* rsum[7];   // replica-0 base; replica stride 7168 floats
    int Hs[7];
    int Ws[7];
    int Wo[7];
    int HoWo[7];
    int stride[7];
    int softmax[7];
    int up[7];
    int Hf[7];
    int Wf2[7];
    float sys[7];
    float sxs[7];
    int blk[8];
};

__global__ __launch_bounds__(256) void k_sample_b(SmP P, const float* __restrict__ bias) {
    int tid = threadIdx.x;
    int wv = tid >> 6, lane = tid & 63;
    int halfp = lane >> 5, l5 = lane & 31;
    int g = l5 >> 3;
    int ch8 = l5 << 3;
    int nb = gridDim.x;
    int per = nb >> 3, rem = nb & 7;
    int xcd = blockIdx.x & 7, bi = blockIdx.x >> 3;
    int logical = xcd * per + min(xcd, rem) + bi;
    int f = (logical >= P.blk[1]) + (logical >= P.blk[2]) + (logical >= P.blk[3]) +
            (logical >= P.blk[4]) + (logical >= P.blk[5]) + (logical >= P.blk[6]);
    const unsigned short* xtb = P.xtb[f];
    const float* om = P.om[f];
    unsigned short* raw = P.raw[f];
    float* stats = P.stats[f];
    float* rsum = P.rsum[f] + (blockIdx.x & 3) * 7168;
    int Hs = P.Hs[f], Ws = P.Ws[f], Wo = P.Wo[f], HoWo = P.HoWo[f];
    int stride = P.stride[f], softmax = P.softmax[f];
    int upf = P.up[f];
    int pix0 = (logical - P.blk[f]) * 8;
    int n = pix0 / HoWo;
    int pixn0 = pix0 - n * HoWo;

    __shared__ float lom[8 * 112];
    __shared__ float lb[108];
    __shared__ float sm[32][9];
    __shared__ float4 lw[288];
    __shared__ ushort4 li[288];
    __shared__ float lstat[32];
    __shared__ float lsum[8][256];
    __shared__ float wup[8];

    // stage OM: 4 group chunks x 8 pixels x 28 floats
    if (tid < 224) {
        int gc = tid / 56, r2 = tid % 56;
        int pp = r2 / 7, c4 = r2 % 7;
        float4 v = *(const float4*)(om + ((size_t)(gc * 4 + n) * HoWo + pixn0 + pp) * 28 +
                                    c4 * 4);
        ((float4*)lom)[pp * 28 + gc * 7 + c4] = v;
    }
    if (tid < 108) lb[tid] = bias[tid];
    if (tid < 32) lstat[tid] = 0.f;
    __syncthreads();

    // masks (softmax / sigmoid) per (pixel, sampling group)
    if (tid < 32) {
        int pp = tid >> 2, gs = tid & 3;
        float mv[9];
#pragma unroll
        for (int k = 0; k < 9; k++) {
            int ch = 72 + gs * 9 + k;
            int gc = ch / 27;
            mv[k] = lom[pp * 112 + gc * 28 + (ch - gc * 27)] + lb[ch];
        }
        if (softmax) {
            float mx = -1e30f;
#pragma unroll
            for (int k = 0; k < 9; k++) mx = fmaxf(mx, mv[k]);
            float ssum = 0.f;
#pragma unroll
            for (int k = 0; k < 9; k++) {
                mv[k] = __expf(mv[k] - mx);
                ssum += mv[k];
            }
            float inv = 1.f / ssum;
#pragma unroll
            for (int k = 0; k < 9; k++) sm[tid][k] = mv[k] * inv;
        } else {
#pragma unroll
            for (int k = 0; k < 9; k++) sm[tid][k] = 1.f / (1.f + __expf(-mv[k]));
        }
    }
    // per-pixel upsample total weight (1 for native feats)
    if (tid < 8) {
        float w = 1.f;
        if (upf) {
            int Ho = HoWo / Wo;
            int pixn = pixn0 + tid;
            int ho = pixn / Wo, wo = pixn - ho * Wo;
            w = upw(ho, Ho, P.Hf[f], P.sys[f]) * upw(wo, Wo, P.Wf2[f], P.sxs[f]);
        }
        wup[tid] = w;
    }
    __syncthreads();

    // bilinear weights + clamped indices per (pixel, group, tap)
    for (int idx = tid; idx < 288; idx += 256) {
        int pg = idx / 9, k = idx % 9;
        int pp = pg >> 2, gs = pg & 3;
        int chy = gs * 18 + 2 * k, chx = chy + 1;
        int gcy = chy / 27, gcx = chx / 27;
        float oy = lom[pp * 112 + gcy * 28 + (chy - gcy * 27)] + lb[chy];
        float ox = lom[pp * 112 + gcx * 28 + (chx - gcx * 27)] + lb[chx];
        int pixn = pixn0 + pp;
        int ho = pixn / Wo, wo = pixn % Wo;
        float py = (float)(ho * stride + k / 3 - 1) + oy;
        float px = (float)(wo * stride + k % 3 - 1) + ox;
        float y0f = floorf(py), x0f = floorf(px);
        int y0 = (int)y0f, x0 = (int)x0f;
        float wy = py - y0f, wx = px - x0f;
        int y1 = y0 + 1, x1 = x0 + 1;
        float v0y = (y0 >= 0 && y0 < Hs) ? 1.f : 0.f;
        float v1y = (y1 >= 0 && y1 < Hs) ? 1.f : 0.f;
        float v0x = (x0 >= 0 && x0 < Ws) ? 1.f : 0.f;
        float v1x = (x1 >= 0 && x1 < Ws) ? 1.f : 0.f;
        int y0c = min(max(y0, 0), Hs - 1), y1c = min(max(y1, 0), Hs - 1);
        int x0c = min(max(x0, 0), Ws - 1), x1c = min(max(x1, 0), Ws - 1);
        float m_ = sm[pg][k];
        float4 w4;
        w4.x = (1.f - wy) * (1.f - wx) * v0y * v0x * m_;
        w4.y = (1.f - wy) * wx * v0y * v1x * m_;
        w4.z = wy * (1.f - wx) * v1y * v0x * m_;
        w4.w = wy * wx * v1y * v1x * m_;
        ushort4 i4;
        i4.x = (unsigned short)(y0c * Ws + x0c);
        i4.y = (unsigned short)(y0c * Ws + x1c);
        i4.z = (unsigned short)(y1c * Ws + x0c);
        i4.w = (unsigned short)(y1c * Ws + x1c);
        lw[pp * 36 + gs * 9 + k] = w4;
        li[pp * 36 + gs * 9 + k] = i4;
    }
    __syncthreads();

    int px = wv * 2 + halfp;
    const unsigned short* xb = xtb + (size_t)n * Hs * Ws * C_ + ch8;
    float4 aL = {0.f, 0.f, 0.f, 0.f}, aH = {0.f, 0.f, 0.f, 0.f};
#pragma unroll
    for (int k = 0; k < 9; k++) {
        float4 w4 = lw[px * 36 + g * 9 + k];
        ushort4 i4 = li[px * 36 + g * 9 + k];
        bf16x8 v0 = *(const bf16x8*)(xb + ((size_t)i4.x << 8));
        bf16x8 v1 = *(const bf16x8*)(xb + ((size_t)i4.y << 8));
        bf16x8 v2 = *(const bf16x8*)(xb + ((size_t)i4.z << 8));
        bf16x8 v3 = *(const bf16x8*)(xb + ((size_t)i4.w << 8));
        aL.x += w4.x * bf2f((unsigned short)v0[0]) + w4.y * bf2f((unsigned short)v1[0]) +
                w4.z * bf2f((unsigned short)v2[0]) + w4.w * bf2f((unsigned short)v3[0]);
        aL.y += w4.x * bf2f((unsigned short)v0[1]) + w4.y * bf2f((unsigned short)v1[1]) +
                w4.z * bf2f((unsigned short)v2[1]) + w4.w * bf2f((unsigned short)v3[1]);
        aL.z += w4.x * bf2f((unsigned short)v0[2]) + w4.y * bf2f((unsigned short)v1[2]) +
                w4.z * bf2f((unsigned short)v2[2]) + w4.w * bf2f((unsigned short)v3[2]);
        aL.w += w4.x * bf2f((unsigned short)v0[3]) + w4.y * bf2f((unsigned short)v1[3]) +
                w4.z * bf2f((unsigned short)v2[3]) + w4.w * bf2f((unsigned short)v3[3]);
        aH.x += w4.x * bf2f((unsigned short)v0[4]) + w4.y * bf2f((unsigned short)v1[4]) +
                w4.z * bf2f((unsigned short)v2[4]) + w4.w * bf2f((unsigned short)v3[4]);
        aH.y += w4.x * bf2f((unsigned short)v0[5]) + w4.y * bf2f((unsigned short)v1[5]) +
                w4.z * bf2f((unsigned short)v2[5]) + w4.w * bf2f((unsigned short)v3[5]);
        aH.z += w4.x * bf2f((unsigned short)v0[6]) + w4.y * bf2f((unsigned short)v1[6]) +
                w4.z * bf2f((unsigned short)v2[6]) + w4.w * bf2f((unsigned short)v3[6]);
        aH.w += w4.x * bf2f((unsigned short)v0[7]) + w4.y * bf2f((unsigned short)v1[7]) +
                w4.z * bf2f((unsigned short)v2[7]) + w4.w * bf2f((unsigned short)v3[7]);
    }
    uint4 ov;
    ov.x = (unsigned)f2bf(aL.x) | ((unsigned)f2bf(aL.y) << 16);
    ov.y = (unsigned)f2bf(aL.z) | ((unsigned)f2bf(aL.w) << 16);
    ov.z = (unsigned)f2bf(aH.x) | ((unsigned)f2bf(aH.y) << 16);
    ov.w = (unsigned)f2bf(aH.z) | ((unsigned)f2bf(aH.w) << 16);
    *(uint4*)(raw + (size_t)(pix0 + px) * C_ + ch8) = ov;
    *(float4*)&lsum[px][ch8] = aL;
    *(float4*)&lsum[px][ch8 + 4] = aH;
    float gs = aL.x + aL.y + aL.z + aL.w + aH.x + aH.y + aH.z + aH.w;
    float gss = aL.x * aL.x + aL.y * aL.y + aL.z * aL.z + aL.w * aL.w + aH.x * aH.x +
                aH.y * aH.y + aH.z * aH.z + aH.w * aH.w;
    gs += __shfl_down(gs, 1, 2);
    gss += __shfl_down(gss, 1, 2);
    if ((lane & 1) == 0) {
        atomicAdd(&lstat[(l5 >> 1) * 2 + 0], gs);
        atomicAdd(&lstat[(l5 >> 1) * 2 + 1], gss);
    }
    __syncthreads();
    if (tid < 32) atomicAdd(&stats[n * 32 + tid], lstat[tid]);
    // weighted per-channel sums (for analytic GN channel-means)
    {
        float s = 0.f;
#pragma unroll
        for (int p2 = 0; p2 < 8; p2++) s += wup[p2] * lsum[p2][tid];
        atomicAdd(&rsum[n * 256 + tid], s);
    }
}

// ------------------- batched per-(level,n) scale-attn + DyReLU coefficients ----
struct CfF {
    const float* rsum;  // replica-0 base; sum 4 replicas stride 7168
    const float* stats;
    const float* gamma;
    const float* beta;
    float cnt;
};
struct CfP {
    CfF ft[3][3];
    int nf[3];
    float inv_nl[3];
    float inv_hw[3];
};

__global__ __launch_bounds__(256) void k_coef_b(CfP P,
                                                const float* __restrict__ sa_w,
                                                const float* __restrict__ sa_b,
                                                const float* __restrict__ fc1_w,
                                                const float* __restrict__ fc1_b,
                                                const float* __restrict__ fc2_w,
                                                const float* __restrict__ fc2_b,
                                                float* __restrict__ coef,
                                                float* __restrict__ af) {
    int lvl = blockIdx.x >> 2;
    int n = blockIdx.x & 3;
    int nf = P.nf[lvl];
    float inv_nl = P.inv_nl[lvl], inv_hw = P.inv_hw[lvl];
    int c = threadIdx.x;
    __shared__ float red[256];
    __shared__ __align__(16) float meanv[256];
    __shared__ __align__(16) float hv[64];
    __shared__ float sa_a[3];
    float cm[3] = {0.f, 0.f, 0.f};
    int gg = c >> 4;
    for (int f = 0; f < nf; f++) {
        CfF s = P.ft[lvl][f];
        float s1 = s.stats[(n * 16 + gg) * 2], s2 = s.stats[(n * 16 + gg) * 2 + 1];
        float mu = s1 / s.cnt;
        float var = s2 / s.cnt - mu * mu;
        float rs = rsqrtf(var + 1e-5f);
        float ga = s.gamma[c] * rs;
        float be = s.beta[c] - mu * ga;
        float wsum = s.rsum[0 * 7168 + n * 256 + c] + s.rsum[1 * 7168 + n * 256 + c] +
                     s.rsum[2 * 7168 + n * 256 + c] + s.rsum[3 * 7168 + n * 256 + c];
        cm[f] = ga * wsum * inv_hw + be;
        red[c] = sa_w[c] * cm[f];
        __syncthreads();
        for (int st = 128; st; st >>= 1) {
            if (c < st) red[c] += red[c + st];
            __syncthreads();
        }
        if (c == 0) {
            float t = fmaxf(red[0] + sa_b[0], 0.f);
            sa_a[f] = fminf(fmaxf((t + 3.f) * (1.f / 6.f), 0.f), 1.f);
        }
        __syncthreads();
    }
    float mv = 0.f;
    for (int f = 0; f < nf; f++) mv += sa_a[f] * cm[f];
    mv *= inv_nl;
    meanv[c] = mv;
    __syncthreads();
    int j = c >> 2, t = c & 3;
    float partial = 0.f;
    {
        const float4* fw = (const float4*)(fc1_w + j * 256 + t * 64);
        const float4* mv4 = (const float4*)(meanv + t * 64);
#pragma unroll
        for (int kk = 0; kk < 16; kk++) {
            float4 a = fw[kk], bb = mv4[kk];
            partial += a.x * bb.x + a.y * bb.y + a.z * bb.z + a.w * bb.w;
        }
    }
    partial += __shfl_down(partial, 2, 4);
    partial += __shfl_down(partial, 1, 4);
    if (t == 0) hv[j] = fmaxf(partial + fc1_b[j], 0.f);
    __syncthreads();
    float zz[4];
#pragma unroll
    for (int i = 0; i < 4; i++) {
        float z = fc2_b[i * 256 + c];
        const float4* f2 = (const float4*)(fc2_w + (size_t)(i * 256 + c) * 64);
        const float4* h4 = (const float4*)hv;
#pragma unroll
        for (int kk = 0; kk < 16; kk++) {
            float4 a = f2[kk], bb = h4[kk];
            z += a.x * bb.x + a.y * bb.y + a.z * bb.z + a.w * bb.w;
        }
        zz[i] = fminf(fmaxf(z + 3.f, 0.f), 6.f) * (1.f / 6.f);
    }
    float* cf = coef + lvl * 4096;
    cf[n * 1024 + 0 * 256 + c] = (zz[0] - 0.5f) * 2.f + 1.f;
    cf[n * 1024 + 1 * 256 + c] = zz[1] - 0.5f;
    cf[n * 1024 + 2 * 256 + c] = (zz[2] - 0.5f) * 2.f;
    cf[n * 1024 + 3 * 256 + c] = zz[3] - 0.5f;
    if (c < 4) af[lvl * 16 + n * 4 + c] = (c < nf) ? sa_a[c] * inv_nl : 0.f;
}

// -------- fused GN affine (+bilinear up) + combine + DyReLU + NCHW store ----
struct StF {
    const unsigned short* raw;  // bf16
    const float* stats;
    const float* gamma;
    const float* beta;
    float cnt;
    int up;
    int Hr;
    int Wr;
    float sys;
    float sxs;
};
struct StP {
    StF ft[3][3];
    float* out[3];
    int nf[3];
    int HW[3];
    int Wf[3];
    int npt[3];
    int blk[4];
};

__global__ __launch_bounds__(256) void k_store_b(StP P, const float* __restrict__ coef,
                                                 const float* __restrict__ af) {
    __shared__ float tile[64][65];
    int b = blockIdx.x;
    int f = (b >= P.blk[1]) + (b >= P.blk[2]);
    int l = b - P.blk[f];
    int npt = P.npt[f], HW = P.HW[f], Wf = P.Wf[f], nf = P.nf[f];
    int n = l / (npt * 4);
    int r_ = l - n * (npt * 4);
    int pt = r_ >> 2;
    int c0 = (r_ & 3) * 64;
    float* out = P.out[f];
    const float* coefL = coef + f * 4096;
    const float* afL = af + f * 16;
    int tid = threadIdx.x;
    int lane16 = tid & 15, prow = tid >> 4;
    int ch4 = c0 + lane16 * 4;
    int gg = ch4 >> 4;
    float a0 = afL[n * 4 + 0], a1f = afL[n * 4 + 1], a2f = afL[n * 4 + 2];
    float4 ca1 = *(const float4*)(coefL + n * 1024 + 0 + ch4);
    float4 cb1 = *(const float4*)(coefL + n * 1024 + 256 + ch4);
    float4 ca2 = *(const float4*)(coefL + n * 1024 + 512 + ch4);
    float4 cb2 = *(const float4*)(coefL + n * 1024 + 768 + ch4);

    StF sA = P.ft[f][0], sB = P.ft[f][1], sC = P.ft[f][2];
    auto mkgb = [&](const StF& s, float4& ga, float4& be) {
        float s1 = s.stats[(n * 16 + gg) * 2], s2 = s.stats[(n * 16 + gg) * 2 + 1];
        float mu = s1 / s.cnt;
        float var = s2 / s.cnt - mu * mu;
        float rs = rsqrtf(var + 1e-5f);
        float4 gm = *(const float4*)(s.gamma + ch4);
        float4 bt = *(const float4*)(s.beta + ch4);
        ga.x = gm.x * rs; be.x = bt.x - mu * ga.x;
        ga.y = gm.y * rs; be.y = bt.y - mu * ga.y;
        ga.z = gm.z * rs; be.z = bt.z - mu * ga.z;
        ga.w = gm.w * rs; be.w = bt.w - mu * ga.w;
    };
    float4 gaA, beA, gaB, beB, gaC = {0, 0, 0, 0}, beC = {0, 0, 0, 0};
    mkgb(sA, gaA, beA);
    mkgb(sB, gaB, beB);
    if (nf > 2) mkgb(sC, gaC, beC);

    auto rdf = [&](const StF& s, int p) -> float4 {
        if (!s.up)
            return bf4(*(const ushort4*)(s.raw + ((size_t)n * HW + p) * C_ + ch4));
        int ho = p / Wf, wo = p - ho * Wf;
        float sy = ho * s.sys, sx = wo * s.sxs;
        int y0 = (int)sy, x0 = (int)sx;
        float fy = sy - y0, fx = sx - x0;
        int y1 = min(y0 + 1, s.Hr - 1), x1 = min(x0 + 1, s.Wr - 1);
        const unsigned short* rb = s.raw + (size_t)n * s.Hr * s.Wr * C_ + ch4;
        float4 v00 = bf4(*(const ushort4*)(rb + (size_t)(y0 * s.Wr + x0) * C_));
        float4 v01 = bf4(*(const ushort4*)(rb + (size_t)(y0 * s.Wr + x1) * C_));
        float4 v10 = bf4(*(const ushort4*)(rb + (size_t)(y1 * s.Wr + x0) * C_));
        float4 v11 = bf4(*(const ushort4*)(rb + (size_t)(y1 * s.Wr + x1) * C_));
        float4 v;
        v.x = (v00.x * (1.f - fy) + v10.x * fy) * (1.f - fx) + (v01.x * (1.f - fy) + v11.x * fy) * fx;
        v.y = (v00.y * (1.f - fy) + v10.y * fy) * (1.f - fx) + (v01.y * (1.f - fy) + v11.y * fy) * fx;
        v.z = (v00.z * (1.f - fy) + v10.z * fy) * (1.f - fx) + (v01.z * (1.f - fy) + v11.z * fy) * fx;
        v.w = (v00.w * (1.f - fy) + v10.w * fy) * (1.f - fx) + (v01.w * (1.f - fy) + v11.w * fy) * fx;
        return v;
    };

#pragma unroll
    for (int pass = 0; pass < 4; pass++) {
        int px = pass * 16 + prow;
        int p = pt * 64 + px;
        if (p < HW) {
            float4 vA = rdf(sA, p);
            float4 fv;
            fv.x = (vA.x * gaA.x + beA.x) * a0;
            fv.y = (vA.y * gaA.y + beA.y) * a0;
            fv.z = (vA.z * gaA.z + beA.z) * a0;
            fv.w = (vA.w * gaA.w + beA.w) * a0;
            float4 vB = rdf(sB, p);
            fv.x += (vB.x * gaB.x + beB.x) * a1f;
            fv.y += (vB.y * gaB.y + beB.y) * a1f;
            fv.z += (vB.z * gaB.z + beB.z) * a1f;
            fv.w += (vB.w * gaB.w + beB.w) * a1f;
            if (nf > 2) {
                float4 vC = rdf(sC, p);
                fv.x += (vC.x * gaC.x + beC.x) * a2f;
                fv.y += (vC.y * gaC.y + beC.y) * a2f;
                fv.z += (vC.z * gaC.z + beC.z) * a2f;
                fv.w += (vC.w * gaC.w + beC.w) * a2f;
            }
            int cr = lane16 * 4;
            tile[cr + 0][px] = fmaxf(fv.x * ca1.x + cb1.x, fv.x * ca2.x + cb2.x);
            tile[cr + 1][px] = fmaxf(fv.y * ca1.y + cb1.y, fv.y * ca2.y + cb2.y);
            tile[cr + 2][px] = fmaxf(fv.z * ca1.z + cb1.z, fv.z * ca2.z + cb2.z);
            tile[cr + 3][px] = fmaxf(fv.w * ca1.w + cb1.w, fv.w * ca2.w + cb2.w);
        }
    }
    __syncthreads();
#pragma unroll
    for (int wp = 0; wp < 4; wp++) {
        int row = wp * 16 + (tid >> 4);
        int px4 = (tid & 15) * 4;
        int p = pt * 64 + px4;
        if (p < HW) {
            float4 r;
            r.x = tile[row][px4 + 0];
            r.y = tile[row][px4 + 1];
            r.z = tile[row][px4 + 2];
            r.w = tile[row][px4 + 3];
            *(float4*)(out + (size_t)(n * C_ + c0 + row) * HW + p) = r;
        }
    }
}

// --------------------------------------------------------------------- host ----
extern "C" void kernel_launch(void* const* d_in, const int* in_sizes, int n_in,
                              void* d_out, int out_size, void* d_ws, size_t ws_size,
                              hipStream_t stream) {
    (void)in_sizes; (void)n_in; (void)out_size; (void)ws_size;
    const float* x0 = (const float*)d_in[0];
    const float* x1 = (const float*)d_in[1];
    const float* x2 = (const float*)d_in[2];
    const float* dw_w_h = (const float*)d_in[3];
    const float* dw_s_h = (const float*)d_in[4];
    const float* dw_b_h = (const float*)d_in[5];
    const float* dw_w_m = (const float*)d_in[6];
    const float* dw_s_m = (const float*)d_in[7];
    const float* dw_b_m = (const float*)d_in[8];
    const float* dw_w_l = (const float*)d_in[9];
    const float* dw_s_l = (const float*)d_in[10];
    const float* dw_b_l = (const float*)d_in[11];
    const float* off_w = (const float*)d_in[12];
    const float* off_b = (const float*)d_in[13];
    const float* gn_g_h = (const float*)d_in[14];
    const float* gn_b_h = (const float*)d_in[15];
    const float* gn_g_m = (const float*)d_in[16];
    const float* gn_b_m = (const float*)d_in[17];
    const float* gn_g_l = (const float*)d_in[18];
    const float* gn_b_l = (const float*)d_in[19];
    const float* sa_w = (const float*)d_in[20];
    const float* sa_b = (const float*)d_in[21];
    const float* fc1_w = (const float*)d_in[22];
    const float* fc1_b = (const float*)d_in[23];
    const float* fc2_w = (const float*)d_in[24];
    const float* fc2_b = (const float*)d_in[25];

    float* ws = (float*)d_ws;
    unsigned short* XTB0 = (unsigned short*)(ws + 0);        // ws[0 .. 3276800)
    unsigned short* XTB1 = (unsigned short*)(ws + 3276800);  // ws[3276800 .. 4096000)
    unsigned short* XTB2 = (unsigned short*)(ws + 4096000);  // ws[4096000 .. 4300800)
    float* SH = ws + 4300800;      // 6553600 floats
    float* FINA = ws + 10854400;   // 6553600
    float* FINB = ws + 17408000;   // 6553600
    float* FINC = ws + 23961600;   // 1638400
    float* WMF = ws + 25600000;    // 36864
    float* DWT = ws + 25636864;    // 6912
    float* STATS = ws + 25643776;  // 896 (7 slots x 128) — zeroed by k_prep

    unsigned short* WMFB = (unsigned short*)WMF;

    float* out0 = (float*)d_out;
    float* out1 = out0 + 6553600;
    float* out2 = out0 + 8192000;

    // OM scratch carved from not-yet-written outputs: [g][n][pix][28]
    float* OM_l0mid = out0;                 // 2867200
    float* OM_l0high = out0 + 2867200;      // 716800
    float* OM_l1mid = out0 + 3584000;       // 716800
    float* OM_l1low = out0 + 4300800;       // 716800 -> ends 5017600 <= 6553600
    float* OM_l1high = out1;                // 179200
    float* OM_l2mid = out1 + 179200;        // 179200
    float* OM_l2low = out1 + 358400;        // 179200 -> ends 537600 <= 1638400

    // raw sample outputs (bf16), same float-offset bases as before
    unsigned short* RAW_l0mid = (unsigned short*)SH;
    unsigned short* RAW_l0high = (unsigned short*)FINC;
    unsigned short* RAW_l1mid = (unsigned short*)FINB;
    unsigned short* RAW_l1low = (unsigned short*)(FINB + 1638400);
    unsigned short* RAW_l1high = (unsigned short*)(FINB + 3276800);
    unsigned short* RAW_l2mid = (unsigned short*)(FINB + 3686400);
    unsigned short* RAW_l2low = (unsigned short*)(FINB + 4096000);
    // 4x replicated RAWSUM in the free FINB tail (zeroed by k_prep)
    float* REP = FINB + 4505600;            // 4 x 7168 = 28672 -> ends 4534272
    // coef/af live in FINA (entirely free now — no dwb staging anymore)
    float* COEF = FINA;                     // 3 * 4096
    float* AF = FINA + 12288;               // 3 * 16

    const float SYS_L0H = (float)(39.0 / 79.0);
    const float SYS_L1H = (float)(19.0 / 39.0);

    k_prep<<<(4 * 32 * 576 + 6912 + 896 + 28672 + 255) / 256, 256, 0, stream>>>(
        off_w, dw_w_h, dw_w_m, dw_w_l, WMFB, DWT, STATS, REP);

    {
        TrP tp{};
        tp.x[0] = x0; tp.xtb[0] = XTB0; tp.H[0] = 80; tp.W[0] = 80; tp.wtc[0] = 3;
        tp.x[1] = x1; tp.xtb[1] = XTB1; tp.H[1] = 40; tp.W[1] = 40; tp.wtc[1] = 2;
        tp.x[2] = x2; tp.xtb[2] = XTB2; tp.H[2] = 20; tp.W[2] = 20; tp.wtc[2] = 1;
        tp.blk[0] = 0; tp.blk[1] = 960; tp.blk[2] = 1280; tp.blk[3] = 1360;
        k_transpose_b<<<dim3(1360, 8), 256, 0, stream>>>(tp);
    }

    auto setod = [&](OdP& op, int i, const unsigned short* xtb, float* om,
                     const float* wdt, const float* sc, const float* bi, int Hs, int Ws,
                     int Wo, int HoWo, int ss, int ths, int tws, int SR, int SC, int nz) {
        op.xtb[i] = xtb; op.om[i] = om; op.wdt[i] = wdt; op.sc[i] = sc; op.bi[i] = bi;
        op.Hs[i] = Hs; op.Ws[i] = Ws; op.Wo[i] = Wo; op.HoWo[i] = HoWo;
        op.ss[i] = ss; op.ths[i] = ths; op.tws[i] = tws;
        op.SR[i] = SR; op.SC[i] = SC; op.Msc[i] = (65536 + SC - 1) / SC;
        op.XC[i] = SC + 2; op.Mxc[i] = (65536 + SC + 1) / (SC + 2);
        op.nz[i] = nz; op.Mnz[i] = (65536 + nz - 1) / nz;
    };

    {   // class A: stride-1 feats (xpatch <= 144 px, patch <= 100 px, 35.1 KB)
        OdP op{};
        setod(op, 0, XTB0, OM_l0mid,  DWT + 1 * 2304, dw_s_m, dw_b_m, 80, 80, 80, 6400,
              0, 3, 3, 10, 10, 10);
        setod(op, 1, XTB1, OM_l0high, DWT + 0 * 2304, dw_s_h, dw_b_h, 40, 40, 40, 1600,
              0, 2, 3, 6, 10, 5);
        setod(op, 2, XTB1, OM_l1mid,  DWT + 1 * 2304, dw_s_m, dw_b_m, 40, 40, 40, 1600,
              0, 2, 3, 6, 10, 5);
        setod(op, 3, XTB2, OM_l1high, DWT + 0 * 2304, dw_s_h, dw_b_h, 20, 20, 20, 400,
              0, 2, 2, 6, 6, 5);
        setod(op, 4, XTB2, OM_l2mid,  DWT + 1 * 2304, dw_s_m, dw_b_m, 20, 20, 20, 400,
              0, 2, 2, 6, 6, 5);
        op.blk[0] = 0; op.blk[1] = 1600; op.blk[2] = 2400; op.blk[3] = 3200;
        op.blk[4] = 3600; op.blk[5] = 4000;
        k_offdw_b<144, 100><<<4000, 256, 0, stream>>>(op, WMFB);
    }
    {   // class B: stride-2 feats (xpatch <= 209 px, patch <= 153 px, 52.1 KB)
        OdP op{};
        setod(op, 0, XTB0, OM_l1low, DWT + 2 * 2304, dw_s_l, dw_b_l, 80, 80, 40, 1600,
              1, 2, 3, 9, 17, 5);
        setod(op, 1, XTB1, OM_l2low, DWT + 2 * 2304, dw_s_l, dw_b_l, 40, 40, 20, 400,
              1, 2, 2, 9, 9, 5);
        op.blk[0] = 0; op.blk[1] = 800; op.blk[2] = 1200; op.blk[3] = 1200;
        op.blk[4] = 1200; op.blk[5] = 1200;
        k_offdw_b<209, 153><<<1200, 256, 0, stream>>>(op, WMFB);
    }

    {
        SmP sp{};
        auto setf = [&](int i, const unsigned short* xtb, const float* om,
                        unsigned short* raw, int slot, int Hs, int Ws, int Wo, int HoWo,
                        int stride, int softmax, int up, int Hf, int Wf2, float sys,
                        float sxs) {
            sp.xtb[i] = xtb; sp.om[i] = om; sp.raw[i] = raw;
            sp.stats[i] = STATS + slot * 128;
            sp.rsum[i] = REP + slot * 1024;
            sp.Hs[i] = Hs; sp.Ws[i] = Ws; sp.Wo[i] = Wo; sp.HoWo[i] = HoWo;
            sp.stride[i] = stride; sp.softmax[i] = softmax;
            sp.up[i] = up; sp.Hf[i] = Hf; sp.Wf2[i] = Wf2;
            sp.sys[i] = sys; sp.sxs[i] = sxs;
        };
        setf(0, XTB0, OM_l0mid,  RAW_l0mid,  0, 80, 80, 80, 6400, 1, 0, 0, 80, 80, 1.f, 1.f);
        setf(1, XTB1, OM_l0high, RAW_l0high, 1, 40, 40, 40, 1600, 1, 1, 1, 80, 80, SYS_L0H, SYS_L0H);
        setf(2, XTB1, OM_l1mid,  RAW_l1mid,  2, 40, 40, 40, 1600, 1, 0, 0, 40, 40, 1.f, 1.f);
        setf(3, XTB0, OM_l1low,  RAW_l1low,  3, 80, 80, 40, 1600, 2, 1, 0, 40, 40, 1.f, 1.f);
        setf(4, XTB2, OM_l1high, RAW_l1high, 4, 20, 20, 20, 400,  1, 1, 1, 40, 40, SYS_L1H, SYS_L1H);
        setf(5, XTB2, OM_l2mid,  RAW_l2mid,  5, 20, 20, 20, 400,  1, 0, 0, 20, 20, 1.f, 1.f);
        setf(6, XTB1, OM_l2low,  RAW_l2low,  6, 40, 40, 20, 400,  2, 1, 0, 20, 20, 1.f, 1.f);
        sp.blk[0] = 0;    sp.blk[1] = 3200; sp.blk[2] = 4000; sp.blk[3] = 4800;
        sp.blk[4] = 5600; sp.blk[5] = 5800; sp.blk[6] = 6000; sp.blk[7] = 6200;
        k_sample_b<<<6200, 256, 0, stream>>>(sp, off_b);
    }

    {
        CfP cp{};
        cp.nf[0] = 2; cp.inv_nl[0] = 0.5f;      cp.inv_hw[0] = 1.f / 6400.f;
        cp.nf[1] = 3; cp.inv_nl[1] = 1.f / 3.f; cp.inv_hw[1] = 1.f / 1600.f;
        cp.nf[2] = 2; cp.inv_nl[2] = 0.5f;      cp.inv_hw[2] = 1.f / 400.f;
        cp.ft[0][0] = {REP + 0 * 1024, STATS + 0 * 128, gn_g_m, gn_b_m, 102400.f};
        cp.ft[0][1] = {REP + 1 * 1024, STATS + 1 * 128, gn_g_h, gn_b_h, 25600.f};
        cp.ft[1][0] = {REP + 2 * 1024, STATS + 2 * 128, gn_g_m, gn_b_m, 25600.f};
        cp.ft[1][1] = {REP + 3 * 1024, STATS + 3 * 128, gn_g_l, gn_b_l, 25600.f};
        cp.ft[1][2] = {REP + 4 * 1024, STATS + 4 * 128, gn_g_h, gn_b_h, 6400.f};
        cp.ft[2][0] = {REP + 5 * 1024, STATS + 5 * 128, gn_g_m, gn_b_m, 6400.f};
        cp.ft[2][1] = {REP + 6 * 1024, STATS + 6 * 128, gn_g_l, gn_b_l, 6400.f};
        k_coef_b<<<12, 256, 0, stream>>>(cp, sa_w, sa_b, fc1_w, fc1_b, fc2_w, fc2_b,
                                         COEF, AF);
    }

    {
        StP st{};
        st.out[0] = out0; st.nf[0] = 2; st.HW[0] = 6400; st.Wf[0] = 80; st.npt[0] = 100;
        st.out[1] = out1; st.nf[1] = 3; st.HW[1] = 1600; st.Wf[1] = 40; st.npt[1] = 25;
        st.out[2] = out2; st.nf[2] = 2; st.HW[2] = 400;  st.Wf[2] = 20; st.npt[2] = 7;
        st.ft[0][0] = {RAW_l0mid,  STATS + 0 * 128, gn_g_m, gn_b_m, 102400.f, 0, 80, 80, 1.f, 1.f};
        st.ft[0][1] = {RAW_l0high, STATS + 1 * 128, gn_g_h, gn_b_h, 25600.f,  1, 40, 40, SYS_L0H, SYS_L0H};
        st.ft[1][0] = {RAW_l1mid,  STATS + 2 * 128, gn_g_m, gn_b_m, 25600.f,  0, 40, 40, 1.f, 1.f};
        st.ft[1][1] = {RAW_l1low,  STATS + 3 * 128, gn_g_l, gn_b_l, 25600.f,  0, 40, 40, 1.f, 1.f};
        st.ft[1][2] = {RAW_l1high, STATS + 4 * 128, gn_g_h, gn_b_h, 6400.f,   1, 20, 20, SYS_L1H, SYS_L1H};
        st.ft[2][0] = {RAW_l2mid,  STATS + 5 * 128, gn_g_m, gn_b_m, 6400.f,   0, 20, 20, 1.f, 1.f};
        st.ft[2][1] = {RAW_l2low,  STATS + 6 * 128, gn_g_l, gn_b_l, 6400.f,   0, 20, 20, 1.f, 1.f};
        st.blk[0] = 0; st.blk[1] = 1600; st.blk[2] = 2000; st.blk[3] = 2112;
        k_store_b<<<2112, 256, 0, stream>>>(st, COEF, AF);
    }
}

// Round 9
// 356.279 us; speedup vs baseline: 1.0228x; 1.0228x over previous
//
#include <hip/hip_runtime.h>
#include <hip/hip_bf16.h>

#define C_ 256
#define G_ 4

typedef __attribute__((ext_vector_type(8))) short bf16x8;
typedef __attribute__((ext_vector_type(4))) float f32x4;

static __device__ __forceinline__ unsigned short f2bf(float x) {
    __hip_bfloat16 h = __float2bfloat16(x);
    return *(unsigned short*)&h;
}
static __device__ __forceinline__ float bf2f(unsigned short u) {
    return __uint_as_float((unsigned)u << 16);
}
static __device__ __forceinline__ float4 bf4(ushort4 u) {
    float4 r;
    r.x = bf2f(u.x);
    r.y = bf2f(u.y);
    r.z = bf2f(u.z);
    r.w = bf2f(u.w);
    return r;
}

// total bilinear weight that source row y receives across all Hf output rows;
// mirrors the store interp exactly (trunc coords, y1 = min(y0+1, Hr-1) clamp).
static __device__ __forceinline__ float upw(int y, int Hr, int Hf, float sys) {
    float inv = 1.f / sys;
    int lo = max(0, (int)((y - 1) * inv) - 1);
    int hi = min(Hf - 1, (int)((y + 1) * inv) + 1);
    float w = 0.f;
    for (int o = lo; o <= hi; o++) {
        float sy = o * sys;
        int y0 = (int)sy;
        float fy = sy - y0;
        int y1 = min(y0 + 1, Hr - 1);
        if (y0 == y) w += 1.f - fy;
        if (y1 == y) w += fy;
    }
    return w;
}

// ---------------------------------------------------------------- prep ----
__global__ void k_prep(const float* __restrict__ off_w, const float* __restrict__ dwh,
                       const float* __restrict__ dwm, const float* __restrict__ dwl,
                       unsigned short* __restrict__ wmf, float* __restrict__ dwt,
                       float* __restrict__ zeros, float* __restrict__ rep,
                       float* __restrict__ upwt) {
    int i = blockIdx.x * 256 + threadIdx.x;
    const int NWM = 4 * 32 * 576;
    if (i < NWM) {
        int g = i / (32 * 576), rem = i % (32 * 576);
        int ol = rem / 576, kk = rem % 576;
        int tap = kk / 64, ic = kk % 64;
        float v = (ol < 27) ? off_w[((size_t)((g * 27 + ol) * 64 + ic)) * 9 + tap] : 0.f;
        wmf[i] = f2bf(v);
    }
    int j = i - NWM;
    if (j >= 0 && j < 3 * 2304) {
        int which = j / 2304, rem = j % 2304;
        int t = rem / 256, c = rem % 256;
        const float* src = (which == 0) ? dwh : (which == 1) ? dwm : dwl;
        dwt[j] = src[c * 9 + t];
    }
    int z = i - NWM - 3 * 2304;
    if (z >= 0 && z < 896) zeros[z] = 0.f;
    int z2 = z - 896;
    if (z2 >= 0 && z2 < 4 * 7168) rep[z2] = 0.f;
    int z3 = z2 - 4 * 7168;
    if (z3 >= 0 && z3 < 64) {
        float w = 0.f;
        if (z3 < 40) w = upw(z3, 40, 80, (float)(39.0 / 79.0));
        else if (z3 < 60) w = upw(z3 - 40, 20, 40, (float)(19.0 / 39.0));
        upwt[z3] = w;
    }
}

// ------------------------------------------------- batched transpose (3 srcs) ----
struct TrP {
    const float* x[3];
    unsigned short* xtb[3];
    int H[3];
    int W[3];
    int wtc[3];
    int blk[4];
};

__global__ __launch_bounds__(256) void k_transpose_b(TrP P) {
    __shared__ float tile[32][33];
    int b = blockIdx.x;
    int f = (b >= P.blk[1]) + (b >= P.blk[2]);
    int l = b - P.blk[f];
    int H = P.H[f], W = P.W[f], wtc = P.wtc[f];
    int nh = l / wtc, wtile = l - nh * wtc;
    int n = nh / H, h = nh % H;
    int w0 = wtile * 32, c0 = blockIdx.y * 32;
    const float* x = P.x[f];
    unsigned short* xtb = P.xtb[f];
    int tid = threadIdx.x;
    int i = tid / 32, j = tid % 32;
#pragma unroll
    for (int r = 0; r < 4; r++) {
        int c = c0 + i + r * 8;
        int w = w0 + j;
        tile[i + r * 8][j] = (w < W) ? x[((size_t)(n * C_ + c) * H + h) * W + w] : 0.f;
    }
    __syncthreads();
    int wj = tid >> 4, ci2 = (tid & 15) * 2;
#pragma unroll
    for (int r = 0; r < 2; r++) {
        int w = w0 + wj + r * 16;
        if (w < W) {
            ushort2 o;
            o.x = f2bf(tile[ci2][wj + r * 16]);
            o.y = f2bf(tile[ci2 + 1][wj + r * 16]);
            *(ushort2*)(xtb + ((size_t)(n * H + h) * W + w) * C_ + c0 + ci2) = o;
        }
    }
}

// ------------------- batched depthwise+SiLU (7 feats, ushort8 lane-split) ----
struct DwP {
    const unsigned short* xtb[7];
    unsigned short* out[7];
    const float* wdt[7];
    const float* sc[7];
    const float* bi[7];
    int H[7];
    int W[7];
    int blk[8];
};

__global__ __launch_bounds__(256) void k_dw_silu_b(DwP P) {
    int b = blockIdx.x;
    int f = (b >= P.blk[1]) + (b >= P.blk[2]) + (b >= P.blk[3]) + (b >= P.blk[4]) +
            (b >= P.blk[5]) + (b >= P.blk[6]);
    int H = P.H[f], W = P.W[f];
    const unsigned short* xtbf = P.xtb[f];
    unsigned short* outf = P.out[f];
    const float* wdt = P.wdt[f];
    int tid = threadIdx.x;
    int wv = tid >> 6, lane = tid & 63;
    int half = lane >> 5, l5 = lane & 31;
    int ch8 = l5 << 3;
    int pix = (b - P.blk[f]) * 8 + wv * 2 + half;
    int w = pix % W, h = (pix / W) % H, n = pix / (W * H);
    const float4 sA = *(const float4*)(P.sc[f] + ch8);
    const float4 sB = *(const float4*)(P.sc[f] + ch8 + 4);
    const float4 bA = *(const float4*)(P.bi[f] + ch8);
    const float4 bB = *(const float4*)(P.bi[f] + ch8 + 4);
    const unsigned short* xb = xtbf + (size_t)n * H * W * C_ + ch8;
    float4 accA = {0.f, 0.f, 0.f, 0.f}, accB = {0.f, 0.f, 0.f, 0.f};
#pragma unroll
    for (int t = 0; t < 9; t++) {
        int hh = h + t / 3 - 1, ww = w + t % 3 - 1;
        if (hh >= 0 && hh < H && ww >= 0 && ww < W) {
            bf16x8 xv = *(const bf16x8*)(xb + (size_t)(hh * W + ww) * C_);
            float4 wa = *(const float4*)(wdt + t * 256 + ch8);
            float4 wb = *(const float4*)(wdt + t * 256 + ch8 + 4);
            accA.x += wa.x * bf2f((unsigned short)xv[0]);
            accA.y += wa.y * bf2f((unsigned short)xv[1]);
            accA.z += wa.z * bf2f((unsigned short)xv[2]);
            accA.w += wa.w * bf2f((unsigned short)xv[3]);
            accB.x += wb.x * bf2f((unsigned short)xv[4]);
            accB.y += wb.y * bf2f((unsigned short)xv[5]);
            accB.z += wb.z * bf2f((unsigned short)xv[6]);
            accB.w += wb.w * bf2f((unsigned short)xv[7]);
        }
    }
    float y0 = accA.x * sA.x + bA.x, y1 = accA.y * sA.y + bA.y;
    float y2 = accA.z * sA.z + bA.z, y3 = accA.w * sA.w + bA.w;
    float y4 = accB.x * sB.x + bB.x, y5 = accB.y * sB.y + bB.y;
    float y6 = accB.z * sB.z + bB.z, y7 = accB.w * sB.w + bB.w;
    y0 = y0 / (1.f + __expf(-y0));
    y1 = y1 / (1.f + __expf(-y1));
    y2 = y2 / (1.f + __expf(-y2));
    y3 = y3 / (1.f + __expf(-y3));
    y4 = y4 / (1.f + __expf(-y4));
    y5 = y5 / (1.f + __expf(-y5));
    y6 = y6 / (1.f + __expf(-y6));
    y7 = y7 / (1.f + __expf(-y7));
    uint4 ov;
    ov.x = (unsigned)f2bf(y0) | ((unsigned)f2bf(y1) << 16);
    ov.y = (unsigned)f2bf(y2) | ((unsigned)f2bf(y3) << 16);
    ov.z = (unsigned)f2bf(y4) | ((unsigned)f2bf(y5) << 16);
    ov.w = (unsigned)f2bf(y6) | ((unsigned)f2bf(y7) << 16);
    *(uint4*)(outf + (size_t)pix * C_ + ch8) = ov;
}

// -------------------- unified grouped offset/mask conv (7 feats, 1 launch) ----
struct OmP7 {
    const unsigned short* dwb[7];
    float* om[7];
    int Hs[7], Ws[7], Wo[7], HoWo[7];
    int ss[7];
    int ths[7], tws[7];
    int SR[7], SC[7], Msc[7];
    int nz[7], Mnz[7];
    int blk[8];
};

__global__ __launch_bounds__(256) void k_offmask_b(OmP7 P,
                                                   const unsigned short* __restrict__ wmf) {
    __shared__ __align__(16) char smem[22032];
    unsigned short* patch = (unsigned short*)smem;
    float* omv = (float*)smem;

    int tid = threadIdx.x;
    int wv = tid >> 6, lane = tid & 63;
    int n16 = lane & 15, q = lane >> 4;
    int b = blockIdx.x;
    int f = (b >= P.blk[1]) + (b >= P.blk[2]) + (b >= P.blk[3]) + (b >= P.blk[4]) +
            (b >= P.blk[5]) + (b >= P.blk[6]);
    int l = b - P.blk[f];
    int n = (l >> 2) & 3, g = l & 3;
    int tile = l >> 4;
    int nz = P.nz[f];
    int ty = (tile * P.Mnz[f]) >> 16;
    int tz = tile - ty * nz;
    int ss = P.ss[f], ths = P.ths[f], tws = P.tws[f];
    int TW = 1 << tws;
    int SR = P.SR[f], SC = P.SC[f], Msc = P.Msc[f];
    int NV = SR * SC;
    int Hs = P.Hs[f], Ws = P.Ws[f], Wo = P.Wo[f], HoWo = P.HoWo[f];
    int ho0 = ty << ths, wo0 = tz << tws;
    int hs0 = (ho0 << ss) - 1, ws0 = (wo0 << ss) - 1;
    const unsigned short* dwb = P.dwb[f];
    float* om = P.om[f];

    for (int idx = tid; idx < NV * 8; idx += 256) {
        int pp = idx >> 3;
        int c8 = (idx & 7) << 3;
        int pq = (pp * Msc) >> 16;
        int hh = hs0 + pq, ww = ws0 + (pp - pq * SC);
        uint4 v = {0u, 0u, 0u, 0u};
        if (hh >= 0 && hh < Hs && ww >= 0 && ww < Ws)
            v = *(const uint4*)(dwb + ((size_t)(n * Hs + hh) * Ws + ww) * C_ + g * 64 + c8);
        *(uint4*)(patch + pp * 72 + c8) = v;
    }
    __syncthreads();

    int bchan = q << 3;
    const unsigned short* wg = wmf + (size_t)g * 32 * 576;
    int TP = 1 << (ths + tws);
    int sc1 = SC, sc2 = SC * 2;

    if (TP == 64) {
        int p = wv * 16 + n16;
        int pr = p >> tws, pc = p & (TW - 1);
        int pixbase = (pr << ss) * SC + (pc << ss);
        f32x4 a0 = {0.f, 0.f, 0.f, 0.f}, a1 = {0.f, 0.f, 0.f, 0.f};
#pragma unroll
        for (int kk = 0; kk < 18; kk++) {
            int tap = kk >> 1;
            int ic0 = (kk & 1) << 5;
            int tr = tap / 3, tc = tap % 3;
            int ppix = pixbase + (tr == 0 ? 0 : (tr == 1 ? sc1 : sc2)) + tc;
            bf16x8 bb = *(const bf16x8*)(patch + ppix * 72 + ic0 + bchan);
            bf16x8 wa0 = *(const bf16x8*)(wg + (size_t)n16 * 576 + kk * 32 + bchan);
            bf16x8 wa1 = *(const bf16x8*)(wg + (size_t)(16 + n16) * 576 + kk * 32 + bchan);
            a0 = __builtin_amdgcn_mfma_f32_16x16x32_bf16(wa0, bb, a0, 0, 0, 0);
            a1 = __builtin_amdgcn_mfma_f32_16x16x32_bf16(wa1, bb, a1, 0, 0, 0);
        }
        __syncthreads();
#pragma unroll
        for (int r = 0; r < 4; r++) {
            int ol0 = q * 4 + r;
            omv[p * 28 + ol0] = a0[r];
            int ol1 = 16 + q * 4 + r;
            if (ol1 < 28) omv[p * 28 + ol1] = a1[r];
        }
    } else {
        int NT = TP >> 3;
        int t = wv;
        bool active = t < NT;
        int ntile = t >> 1, mtile = t & 1;
        int p = ntile * 16 + n16;
        int pr = p >> tws, pc = p & (TW - 1);
        int pixbase = (pr << ss) * SC + (pc << ss);
        f32x4 acc = {0.f, 0.f, 0.f, 0.f};
        if (active) {
#pragma unroll
            for (int kk = 0; kk < 18; kk++) {
                int tap = kk >> 1;
                int ic0 = (kk & 1) << 5;
                int tr = tap / 3, tc = tap % 3;
                int ppix = pixbase + (tr == 0 ? 0 : (tr == 1 ? sc1 : sc2)) + tc;
                bf16x8 bb = *(const bf16x8*)(patch + ppix * 72 + ic0 + bchan);
                bf16x8 wa = *(const bf16x8*)(wg + (size_t)(mtile * 16 + n16) * 576 +
                                             kk * 32 + bchan);
                acc = __builtin_amdgcn_mfma_f32_16x16x32_bf16(wa, bb, acc, 0, 0, 0);
            }
        }
        __syncthreads();
        if (active) {
#pragma unroll
            for (int r = 0; r < 4; r++) {
                int ol = mtile * 16 + q * 4 + r;
                if (ol < 28) omv[p * 28 + ol] = acc[r];
            }
        }
    }
    __syncthreads();

    float* omg = om + ((size_t)(g * 4 + n)) * HoWo * 28;
    for (int idx = tid; idx < TP * 7; idx += 256) {
        int p = (idx * 9363) >> 16;
        int c4 = idx - p * 7;
        int ho = ho0 + (p >> tws), wo = wo0 + (p & (TW - 1));
        int pixn = ho * Wo + wo;
        *(float4*)(omg + (size_t)pixn * 28 + c4 * 4) = *(float4*)(omv + p * 28 + c4 * 4);
    }
}

// -------------- batched DCNv3 sample (7 feats) + per-channel weighted sums ----
// rsum reduction: wup applied in-register, 2-pixel fold via shfl_xor(32),
// lsum4[4][256] (4 KB) instead of [8][256]. wup from precomputed tables.
struct SmP {
    const unsigned short* xtb[7];
    const float* om[7];
    unsigned short* raw[7];
    float* stats[7];
    float* rsum[7];   // replica-0 base; replica stride 7168 floats
    const float* upt[7];
    int Hs[7];
    int Ws[7];
    int Wo[7];
    int HoWo[7];
    int stride[7];
    int softmax[7];
    int up[7];
    int blk[8];
};

__global__ __launch_bounds__(256) void k_sample_b(SmP P, const float* __restrict__ bias) {
    int tid = threadIdx.x;
    int wv = tid >> 6, lane = tid & 63;
    int halfp = lane >> 5, l5 = lane & 31;
    int g = l5 >> 3;
    int ch8 = l5 << 3;
    int nb = gridDim.x;
    int per = nb >> 3, rem = nb & 7;
    int xcd = blockIdx.x & 7, bi = blockIdx.x >> 3;
    int logical = xcd * per + min(xcd, rem) + bi;
    int f = (logical >= P.blk[1]) + (logical >= P.blk[2]) + (logical >= P.blk[3]) +
            (logical >= P.blk[4]) + (logical >= P.blk[5]) + (logical >= P.blk[6]);
    const unsigned short* xtb = P.xtb[f];
    const float* om = P.om[f];
    unsigned short* raw = P.raw[f];
    float* stats = P.stats[f];
    float* rsum = P.rsum[f] + (blockIdx.x & 3) * 7168;
    int Hs = P.Hs[f], Ws = P.Ws[f], Wo = P.Wo[f], HoWo = P.HoWo[f];
    int stride = P.stride[f], softmax = P.softmax[f];
    int upf = P.up[f];
    int pix0 = (logical - P.blk[f]) * 8;
    int n = pix0 / HoWo;
    int pixn0 = pix0 - n * HoWo;

    __shared__ float lom[8 * 112];
    __shared__ float lb[108];
    __shared__ float sm[32][9];
    __shared__ float4 lw[288];
    __shared__ ushort4 li[288];
    __shared__ float lstat[32];
    __shared__ float lsum4[4][256];
    __shared__ float wup[8];

    // stage OM: 4 group chunks x 8 pixels x 28 floats
    if (tid < 224) {
        int gc = tid / 56, r2 = tid % 56;
        int pp = r2 / 7, c4 = r2 % 7;
        float4 v = *(const float4*)(om + ((size_t)(gc * 4 + n) * HoWo + pixn0 + pp) * 28 +
                                    c4 * 4);
        ((float4*)lom)[pp * 28 + gc * 7 + c4] = v;
    }
    if (tid < 108) lb[tid] = bias[tid];
    if (tid < 32) lstat[tid] = 0.f;
    __syncthreads();

    // masks (softmax / sigmoid) per (pixel, sampling group)
    if (tid < 32) {
        int pp = tid >> 2, gs = tid & 3;
        float mv[9];
#pragma unroll
        for (int k = 0; k < 9; k++) {
            int ch = 72 + gs * 9 + k;
            int gc = ch / 27;
            mv[k] = lom[pp * 112 + gc * 28 + (ch - gc * 27)] + lb[ch];
        }
        if (softmax) {
            float mx = -1e30f;
#pragma unroll
            for (int k = 0; k < 9; k++) mx = fmaxf(mx, mv[k]);
            float ssum = 0.f;
#pragma unroll
            for (int k = 0; k < 9; k++) {
                mv[k] = __expf(mv[k] - mx);
                ssum += mv[k];
            }
            float inv = 1.f / ssum;
#pragma unroll
            for (int k = 0; k < 9; k++) sm[tid][k] = mv[k] * inv;
        } else {
#pragma unroll
            for (int k = 0; k < 9; k++) sm[tid][k] = 1.f / (1.f + __expf(-mv[k]));
        }
    }
    // per-pixel upsample total weight (1 for native feats; table lookup)
    if (tid < 8) {
        float w = 1.f;
        if (upf) {
            int pixn = pixn0 + tid;
            int ho = pixn / Wo, wo = pixn - ho * Wo;
            const float* t = P.upt[f];
            w = t[ho] * t[wo];
        }
        wup[tid] = w;
    }
    __syncthreads();

    // bilinear weights + clamped indices per (pixel, group, tap)
    for (int idx = tid; idx < 288; idx += 256) {
        int pg = idx / 9, k = idx % 9;
        int pp = pg >> 2, gs = pg & 3;
        int chy = gs * 18 + 2 * k, chx = chy + 1;
        int gcy = chy / 27, gcx = chx / 27;
        float oy = lom[pp * 112 + gcy * 28 + (chy - gcy * 27)] + lb[chy];
        float ox = lom[pp * 112 + gcx * 28 + (chx - gcx * 27)] + lb[chx];
        int pixn = pixn0 + pp;
        int ho = pixn / Wo, wo = pixn % Wo;
        float py = (float)(ho * stride + k / 3 - 1) + oy;
        float px = (float)(wo * stride + k % 3 - 1) + ox;
        float y0f = floorf(py), x0f = floorf(px);
        int y0 = (int)y0f, x0 = (int)x0f;
        float wy = py - y0f, wx = px - x0f;
        int y1 = y0 + 1, x1 = x0 + 1;
        float v0y = (y0 >= 0 && y0 < Hs) ? 1.f : 0.f;
        float v1y = (y1 >= 0 && y1 < Hs) ? 1.f : 0.f;
        float v0x = (x0 >= 0 && x0 < Ws) ? 1.f : 0.f;
        float v1x = (x1 >= 0 && x1 < Ws) ? 1.f : 0.f;
        int y0c = min(max(y0, 0), Hs - 1), y1c = min(max(y1, 0), Hs - 1);
        int x0c = min(max(x0, 0), Ws - 1), x1c = min(max(x1, 0), Ws - 1);
        float m_ = sm[pg][k];
        float4 w4;
        w4.x = (1.f - wy) * (1.f - wx) * v0y * v0x * m_;
        w4.y = (1.f - wy) * wx * v0y * v1x * m_;
        w4.z = wy * (1.f - wx) * v1y * v0x * m_;
        w4.w = wy * wx * v1y * v1x * m_;
        ushort4 i4;
        i4.x = (unsigned short)(y0c * Ws + x0c);
        i4.y = (unsigned short)(y0c * Ws + x1c);
        i4.z = (unsigned short)(y1c * Ws + x0c);
        i4.w = (unsigned short)(y1c * Ws + x1c);
        lw[pp * 36 + gs * 9 + k] = w4;
        li[pp * 36 + gs * 9 + k] = i4;
    }
    __syncthreads();

    int px = wv * 2 + halfp;
    const unsigned short* xb = xtb + (size_t)n * Hs * Ws * C_ + ch8;
    float4 aL = {0.f, 0.f, 0.f, 0.f}, aH = {0.f, 0.f, 0.f, 0.f};
#pragma unroll
    for (int k = 0; k < 9; k++) {
        float4 w4 = lw[px * 36 + g * 9 + k];
        ushort4 i4 = li[px * 36 + g * 9 + k];
        bf16x8 v0 = *(const bf16x8*)(xb + ((size_t)i4.x << 8));
        bf16x8 v1 = *(const bf16x8*)(xb + ((size_t)i4.y << 8));
        bf16x8 v2 = *(const bf16x8*)(xb + ((size_t)i4.z << 8));
        bf16x8 v3 = *(const bf16x8*)(xb + ((size_t)i4.w << 8));
        aL.x += w4.x * bf2f((unsigned short)v0[0]) + w4.y * bf2f((unsigned short)v1[0]) +
                w4.z * bf2f((unsigned short)v2[0]) + w4.w * bf2f((unsigned short)v3[0]);
        aL.y += w4.x * bf2f((unsigned short)v0[1]) + w4.y * bf2f((unsigned short)v1[1]) +
                w4.z * bf2f((unsigned short)v2[1]) + w4.w * bf2f((unsigned short)v3[1]);
        aL.z += w4.x * bf2f((unsigned short)v0[2]) + w4.y * bf2f((unsigned short)v1[2]) +
                w4.z * bf2f((unsigned short)v2[2]) + w4.w * bf2f((unsigned short)v3[2]);
        aL.w += w4.x * bf2f((unsigned short)v0[3]) + w4.y * bf2f((unsigned short)v1[3]) +
                w4.z * bf2f((unsigned short)v2[3]) + w4.w * bf2f((unsigned short)v3[3]);
        aH.x += w4.x * bf2f((unsigned short)v0[4]) + w4.y * bf2f((unsigned short)v1[4]) +
                w4.z * bf2f((unsigned short)v2[4]) + w4.w * bf2f((unsigned short)v3[4]);
        aH.y += w4.x * bf2f((unsigned short)v0[5]) + w4.y * bf2f((unsigned short)v1[5]) +
                w4.z * bf2f((unsigned short)v2[5]) + w4.w * bf2f((unsigned short)v3[5]);
        aH.z += w4.x * bf2f((unsigned short)v0[6]) + w4.y * bf2f((unsigned short)v1[6]) +
                w4.z * bf2f((unsigned short)v2[6]) + w4.w * bf2f((unsigned short)v3[6]);
        aH.w += w4.x * bf2f((unsigned short)v0[7]) + w4.y * bf2f((unsigned short)v1[7]) +
                w4.z * bf2f((unsigned short)v2[7]) + w4.w * bf2f((unsigned short)v3[7]);
    }
    uint4 ov;
    ov.x = (unsigned)f2bf(aL.x) | ((unsigned)f2bf(aL.y) << 16);
    ov.y = (unsigned)f2bf(aL.z) | ((unsigned)f2bf(aL.w) << 16);
    ov.z = (unsigned)f2bf(aH.x) | ((unsigned)f2bf(aH.y) << 16);
    ov.w = (unsigned)f2bf(aH.z) | ((unsigned)f2bf(aH.w) << 16);
    *(uint4*)(raw + (size_t)(pix0 + px) * C_ + ch8) = ov;

    // weighted channel sums: fold the wave's 2 pixels via xor-32 shuffle
    {
        float wq = wup[px];
        float s0 = wq * aL.x, s1 = wq * aL.y, s2 = wq * aL.z, s3 = wq * aL.w;
        float s4 = wq * aH.x, s5 = wq * aH.y, s6 = wq * aH.z, s7 = wq * aH.w;
        s0 += __shfl_xor(s0, 32);
        s1 += __shfl_xor(s1, 32);
        s2 += __shfl_xor(s2, 32);
        s3 += __shfl_xor(s3, 32);
        s4 += __shfl_xor(s4, 32);
        s5 += __shfl_xor(s5, 32);
        s6 += __shfl_xor(s6, 32);
        s7 += __shfl_xor(s7, 32);
        if (halfp == 0) {
            float4 a = {s0, s1, s2, s3}, b2 = {s4, s5, s6, s7};
            *(float4*)&lsum4[wv][ch8] = a;
            *(float4*)&lsum4[wv][ch8 + 4] = b2;
        }
    }
    float gs = aL.x + aL.y + aL.z + aL.w + aH.x + aH.y + aH.z + aH.w;
    float gss = aL.x * aL.x + aL.y * aL.y + aL.z * aL.z + aL.w * aL.w + aH.x * aH.x +
                aH.y * aH.y + aH.z * aH.z + aH.w * aH.w;
    gs += __shfl_down(gs, 1, 2);
    gss += __shfl_down(gss, 1, 2);
    if ((lane & 1) == 0) {
        atomicAdd(&lstat[(l5 >> 1) * 2 + 0], gs);
        atomicAdd(&lstat[(l5 >> 1) * 2 + 1], gss);
    }
    __syncthreads();
    if (tid < 32) atomicAdd(&stats[n * 32 + tid], lstat[tid]);
    // weighted per-channel sums (for analytic GN channel-means)
    {
        float s = lsum4[0][tid] + lsum4[1][tid] + lsum4[2][tid] + lsum4[3][tid];
        atomicAdd(&rsum[n * 256 + tid], s);
    }
}

// ------------------- batched per-(level,n) scale-attn + DyReLU coefficients ----
struct CfF {
    const float* rsum;  // replica-0 base; sum 4 replicas stride 7168
    const float* stats;
    const float* gamma;
    const float* beta;
    float cnt;
};
struct CfP {
    CfF ft[3][3];
    int nf[3];
    float inv_nl[3];
    float inv_hw[3];
};

__global__ __launch_bounds__(256) void k_coef_b(CfP P,
                                                const float* __restrict__ sa_w,
                                                const float* __restrict__ sa_b,
                                                const float* __restrict__ fc1_w,
                                                const float* __restrict__ fc1_b,
                                                const float* __restrict__ fc2_w,
                                                const float* __restrict__ fc2_b,
                                                float* __restrict__ coef,
                                                float* __restrict__ af) {
    int lvl = blockIdx.x >> 2;
    int n = blockIdx.x & 3;
    int nf = P.nf[lvl];
    float inv_nl = P.inv_nl[lvl], inv_hw = P.inv_hw[lvl];
    int c = threadIdx.x;
    __shared__ float red[256];
    __shared__ __align__(16) float meanv[256];
    __shared__ __align__(16) float hv[64];
    __shared__ float sa_a[3];
    float cm[3] = {0.f, 0.f, 0.f};
    int gg = c >> 4;
    for (int f = 0; f < nf; f++) {
        CfF s = P.ft[lvl][f];
        float s1 = s.stats[(n * 16 + gg) * 2], s2 = s.stats[(n * 16 + gg) * 2 + 1];
        float mu = s1 / s.cnt;
        float var = s2 / s.cnt - mu * mu;
        float rs = rsqrtf(var + 1e-5f);
        float ga = s.gamma[c] * rs;
        float be = s.beta[c] - mu * ga;
        float wsum = s.rsum[0 * 7168 + n * 256 + c] + s.rsum[1 * 7168 + n * 256 + c] +
                     s.rsum[2 * 7168 + n * 256 + c] + s.rsum[3 * 7168 + n * 256 + c];
        cm[f] = ga * wsum * inv_hw + be;
        red[c] = sa_w[c] * cm[f];
        __syncthreads();
        for (int st = 128; st; st >>= 1) {
            if (c < st) red[c] += red[c + st];
            __syncthreads();
        }
        if (c == 0) {
            float t = fmaxf(red[0] + sa_b[0], 0.f);
            sa_a[f] = fminf(fmaxf((t + 3.f) * (1.f / 6.f), 0.f), 1.f);
        }
        __syncthreads();
    }
    float mv = 0.f;
    for (int f = 0; f < nf; f++) mv += sa_a[f] * cm[f];
    mv *= inv_nl;
    meanv[c] = mv;
    __syncthreads();
    int j = c >> 2, t = c & 3;
    float partial = 0.f;
    {
        const float4* fw = (const float4*)(fc1_w + j * 256 + t * 64);
        const float4* mv4 = (const float4*)(meanv + t * 64);
#pragma unroll
        for (int kk = 0; kk < 16; kk++) {
            float4 a = fw[kk], bb = mv4[kk];
            partial += a.x * bb.x + a.y * bb.y + a.z * bb.z + a.w * bb.w;
        }
    }
    partial += __shfl_down(partial, 2, 4);
    partial += __shfl_down(partial, 1, 4);
    if (t == 0) hv[j] = fmaxf(partial + fc1_b[j], 0.f);
    __syncthreads();
    float zz[4];
#pragma unroll
    for (int i = 0; i < 4; i++) {
        float z = fc2_b[i * 256 + c];
        const float4* f2 = (const float4*)(fc2_w + (size_t)(i * 256 + c) * 64);
        const float4* h4 = (const float4*)hv;
#pragma unroll
        for (int kk = 0; kk < 16; kk++) {
            float4 a = f2[kk], bb = h4[kk];
            z += a.x * bb.x + a.y * bb.y + a.z * bb.z + a.w * bb.w;
        }
        zz[i] = fminf(fmaxf(z + 3.f, 0.f), 6.f) * (1.f / 6.f);
    }
    float* cf = coef + lvl * 4096;
    cf[n * 1024 + 0 * 256 + c] = (zz[0] - 0.5f) * 2.f + 1.f;
    cf[n * 1024 + 1 * 256 + c] = zz[1] - 0.5f;
    cf[n * 1024 + 2 * 256 + c] = (zz[2] - 0.5f) * 2.f;
    cf[n * 1024 + 3 * 256 + c] = zz[3] - 0.5f;
    if (c < 4) af[lvl * 16 + n * 4 + c] = (c < nf) ? sa_a[c] * inv_nl : 0.f;
}

// -------- fused GN affine (+bilinear up) + combine + DyReLU + NCHW store ----
struct StF {
    const unsigned short* raw;  // bf16
    const float* stats;
    const float* gamma;
    const float* beta;
    float cnt;
    int up;
    int Hr;
    int Wr;
    float sys;
    float sxs;
};
struct StP {
    StF ft[3][3];
    float* out[3];
    int nf[3];
    int HW[3];
    int Wf[3];
    int npt[3];
    int blk[4];
};

__global__ __launch_bounds__(256) void k_store_b(StP P, const float* __restrict__ coef,
                                                 const float* __restrict__ af) {
    __shared__ float tile[64][65];
    int b = blockIdx.x;
    int f = (b >= P.blk[1]) + (b >= P.blk[2]);
    int l = b - P.blk[f];
    int npt = P.npt[f], HW = P.HW[f], Wf = P.Wf[f], nf = P.nf[f];
    int n = l / (npt * 4);
    int r_ = l - n * (npt * 4);
    int pt = r_ >> 2;
    int c0 = (r_ & 3) * 64;
    float* out = P.out[f];
    const float* coefL = coef + f * 4096;
    const float* afL = af + f * 16;
    int tid = threadIdx.x;
    int lane16 = tid & 15, prow = tid >> 4;
    int ch4 = c0 + lane16 * 4;
    int gg = ch4 >> 4;
    float a0 = afL[n * 4 + 0], a1f = afL[n * 4 + 1], a2f = afL[n * 4 + 2];
    float4 ca1 = *(const float4*)(coefL + n * 1024 + 0 + ch4);
    float4 cb1 = *(const float4*)(coefL + n * 1024 + 256 + ch4);
    float4 ca2 = *(const float4*)(coefL + n * 1024 + 512 + ch4);
    float4 cb2 = *(const float4*)(coefL + n * 1024 + 768 + ch4);

    StF sA = P.ft[f][0], sB = P.ft[f][1], sC = P.ft[f][2];
    auto mkgb = [&](const StF& s, float4& ga, float4& be) {
        float s1 = s.stats[(n * 16 + gg) * 2], s2 = s.stats[(n * 16 + gg) * 2 + 1];
        float mu = s1 / s.cnt;
        float var = s2 / s.cnt - mu * mu;
        float rs = rsqrtf(var + 1e-5f);
        float4 gm = *(const float4*)(s.gamma + ch4);
        float4 bt = *(const float4*)(s.beta + ch4);
        ga.x = gm.x * rs; be.x = bt.x - mu * ga.x;
        ga.y = gm.y * rs; be.y = bt.y - mu * ga.y;
        ga.z = gm.z * rs; be.z = bt.z - mu * ga.z;
        ga.w = gm.w * rs; be.w = bt.w - mu * ga.w;
    };
    float4 gaA, beA, gaB, beB, gaC = {0, 0, 0, 0}, beC = {0, 0, 0, 0};
    mkgb(sA, gaA, beA);
    mkgb(sB, gaB, beB);
    if (nf > 2) mkgb(sC, gaC, beC);

    auto rdf = [&](const StF& s, int p) -> float4 {
        if (!s.up)
            return bf4(*(const ushort4*)(s.raw + ((size_t)n * HW + p) * C_ + ch4));
        int ho = p / Wf, wo = p - ho * Wf;
        float sy = ho * s.sys, sx = wo * s.sxs;
        int y0 = (int)sy, x0 = (int)sx;
        float fy = sy - y0, fx = sx - x0;
        int y1 = min(y0 + 1, s.Hr - 1), x1 = min(x0 + 1, s.Wr - 1);
        const unsigned short* rb = s.raw + (size_t)n * s.Hr * s.Wr * C_ + ch4;
        float4 v00 = bf4(*(const ushort4*)(rb + (size_t)(y0 * s.Wr + x0) * C_));
        float4 v01 = bf4(*(const ushort4*)(rb + (size_t)(y0 * s.Wr + x1) * C_));
        float4 v10 = bf4(*(const ushort4*)(rb + (size_t)(y1 * s.Wr + x0) * C_));
        float4 v11 = bf4(*(const ushort4*)(rb + (size_t)(y1 * s.Wr + x1) * C_));
        float4 v;
        v.x = (v00.x * (1.f - fy) + v10.x * fy) * (1.f - fx) + (v01.x * (1.f - fy) + v11.x * fy) * fx;
        v.y = (v00.y * (1.f - fy) + v10.y * fy) * (1.f - fx) + (v01.y * (1.f - fy) + v11.y * fy) * fx;
        v.z = (v00.z * (1.f - fy) + v10.z * fy) * (1.f - fx) + (v01.z * (1.f - fy) + v11.z * fy) * fx;
        v.w = (v00.w * (1.f - fy) + v10.w * fy) * (1.f - fx) + (v01.w * (1.f - fy) + v11.w * fy) * fx;
        return v;
    };

#pragma unroll
    for (int pass = 0; pass < 4; pass++) {
        int px = pass * 16 + prow;
        int p = pt * 64 + px;
        if (p < HW) {
            float4 vA = rdf(sA, p);
            float4 fv;
            fv.x = (vA.x * gaA.x + beA.x) * a0;
            fv.y = (vA.y * gaA.y + beA.y) * a0;
            fv.z = (vA.z * gaA.z + beA.z) * a0;
            fv.w = (vA.w * gaA.w + beA.w) * a0;
            float4 vB = rdf(sB, p);
            fv.x += (vB.x * gaB.x + beB.x) * a1f;
            fv.y += (vB.y * gaB.y + beB.y) * a1f;
            fv.z += (vB.z * gaB.z + beB.z) * a1f;
            fv.w += (vB.w * gaB.w + beB.w) * a1f;
            if (nf > 2) {
                float4 vC = rdf(sC, p);
                fv.x += (vC.x * gaC.x + beC.x) * a2f;
                fv.y += (vC.y * gaC.y + beC.y) * a2f;
                fv.z += (vC.z * gaC.z + beC.z) * a2f;
                fv.w += (vC.w * gaC.w + beC.w) * a2f;
            }
            int cr = lane16 * 4;
            tile[cr + 0][px] = fmaxf(fv.x * ca1.x + cb1.x, fv.x * ca2.x + cb2.x);
            tile[cr + 1][px] = fmaxf(fv.y * ca1.y + cb1.y, fv.y * ca2.y + cb2.y);
            tile[cr + 2][px] = fmaxf(fv.z * ca1.z + cb1.z, fv.z * ca2.z + cb2.z);
            tile[cr + 3][px] = fmaxf(fv.w * ca1.w + cb1.w, fv.w * ca2.w + cb2.w);
        }
    }
    __syncthreads();
#pragma unroll
    for (int wp = 0; wp < 4; wp++) {
        int row = wp * 16 + (tid >> 4);
        int px4 = (tid & 15) * 4;
        int p = pt * 64 + px4;
        if (p < HW) {
            float4 r;
            r.x = tile[row][px4 + 0];
            r.y = tile[row][px4 + 1];
            r.z = tile[row][px4 + 2];
            r.w = tile[row][px4 + 3];
            *(float4*)(out + (size_t)(n * C_ + c0 + row) * HW + p) = r;
        }
    }
}

// --------------------------------------------------------------------- host ----
extern "C" void kernel_launch(void* const* d_in, const int* in_sizes, int n_in,
                              void* d_out, int out_size, void* d_ws, size_t ws_size,
                              hipStream_t stream) {
    (void)in_sizes; (void)n_in; (void)out_size; (void)ws_size;
    const float* x0 = (const float*)d_in[0];
    const float* x1 = (const float*)d_in[1];
    const float* x2 = (const float*)d_in[2];
    const float* dw_w_h = (const float*)d_in[3];
    const float* dw_s_h = (const float*)d_in[4];
    const float* dw_b_h = (const float*)d_in[5];
    const float* dw_w_m = (const float*)d_in[6];
    const float* dw_s_m = (const float*)d_in[7];
    const float* dw_b_m = (const float*)d_in[8];
    const float* dw_w_l = (const float*)d_in[9];
    const float* dw_s_l = (const float*)d_in[10];
    const float* dw_b_l = (const float*)d_in[11];
    const float* off_w = (const float*)d_in[12];
    const float* off_b = (const float*)d_in[13];
    const float* gn_g_h = (const float*)d_in[14];
    const float* gn_b_h = (const float*)d_in[15];
    const float* gn_g_m = (const float*)d_in[16];
    const float* gn_b_m = (const float*)d_in[17];
    const float* gn_g_l = (const float*)d_in[18];
    const float* gn_b_l = (const float*)d_in[19];
    const float* sa_w = (const float*)d_in[20];
    const float* sa_b = (const float*)d_in[21];
    const float* fc1_w = (const float*)d_in[22];
    const float* fc1_b = (const float*)d_in[23];
    const float* fc2_w = (const float*)d_in[24];
    const float* fc2_b = (const float*)d_in[25];

    float* ws = (float*)d_ws;
    unsigned short* XTB0 = (unsigned short*)(ws + 0);        // ws[0 .. 3276800)
    unsigned short* XTB1 = (unsigned short*)(ws + 3276800);  // ws[3276800 .. 4096000)
    unsigned short* XTB2 = (unsigned short*)(ws + 4096000);  // ws[4096000 .. 4300800)
    float* SH = ws + 4300800;      // 6553600 floats
    float* FINA = ws + 10854400;   // 6553600
    float* FINB = ws + 17408000;   // 6553600
    float* FINC = ws + 23961600;   // 1638400
    float* WMF = ws + 25600000;    // 36864
    float* DWT = ws + 25636864;    // 6912
    float* STATS = ws + 25643776;  // 896 (7 slots x 128) — zeroed by k_prep

    unsigned short* SHB = (unsigned short*)SH;
    unsigned short* FINAB = (unsigned short*)FINA;
    unsigned short* WMFB = (unsigned short*)WMF;

    float* out0 = (float*)d_out;
    float* out1 = out0 + 6553600;
    float* out2 = out0 + 8192000;

    // OM scratch carved from not-yet-written outputs: [g][n][pix][28]
    float* OM_l0mid = out0;                 // 2867200
    float* OM_l0high = out0 + 2867200;      // 716800
    float* OM_l1mid = out0 + 3584000;       // 716800
    float* OM_l1low = out0 + 4300800;       // 716800 -> ends 5017600 <= 6553600
    float* OM_l1high = out1;                // 179200
    float* OM_l2mid = out1 + 179200;        // 179200
    float* OM_l2low = out1 + 358400;        // 179200 -> ends 537600 <= 1638400

    // raw sample outputs (bf16), same float-offset bases as before
    unsigned short* RAW_l0mid = (unsigned short*)SH;
    unsigned short* RAW_l0high = (unsigned short*)FINC;
    unsigned short* RAW_l1mid = (unsigned short*)FINB;
    unsigned short* RAW_l1low = (unsigned short*)(FINB + 1638400);
    unsigned short* RAW_l1high = (unsigned short*)(FINB + 3276800);
    unsigned short* RAW_l2mid = (unsigned short*)(FINB + 3686400);
    unsigned short* RAW_l2low = (unsigned short*)(FINB + 4096000);
    // 4x replicated RAWSUM + upsample-weight tables in the free FINB tail
    float* REP = FINB + 4505600;            // 4 x 7168 = 28672 -> ends 4534272
    float* UPW = FINB + 4534272;            // 64 floats (40 for l0high, 20 for l1high)
    // coef/af live in FINA (free after offmask consumed the DWB tiles there)
    float* COEF = FINA;                     // 3 * 4096
    float* AF = FINA + 12288;               // 3 * 16

    const float SYS_L0H = (float)(39.0 / 79.0);
    const float SYS_L1H = (float)(19.0 / 39.0);

    k_prep<<<(4 * 32 * 576 + 6912 + 896 + 28672 + 64 + 255) / 256, 256, 0, stream>>>(
        off_w, dw_w_h, dw_w_m, dw_w_l, WMFB, DWT, STATS, REP, UPW);

    {
        TrP tp{};
        tp.x[0] = x0; tp.xtb[0] = XTB0; tp.H[0] = 80; tp.W[0] = 80; tp.wtc[0] = 3;
        tp.x[1] = x1; tp.xtb[1] = XTB1; tp.H[1] = 40; tp.W[1] = 40; tp.wtc[1] = 2;
        tp.x[2] = x2; tp.xtb[2] = XTB2; tp.H[2] = 20; tp.W[2] = 20; tp.wtc[2] = 1;
        tp.blk[0] = 0; tp.blk[1] = 960; tp.blk[2] = 1280; tp.blk[3] = 1360;
        k_transpose_b<<<dim3(1360, 8), 256, 0, stream>>>(tp);
    }

    // dwb placements (bf16 elem offsets); consumed by offmask
    unsigned short* DWB_x0mid = SHB;                  // 6553600 elems
    unsigned short* DWB_x0low = SHB + 6553600;        // 6553600
    unsigned short* DWB_x1high = FINAB;               // 1638400
    unsigned short* DWB_x1mid = FINAB + 1638400;      // 1638400
    unsigned short* DWB_x1low = FINAB + 3276800;      // 1638400
    unsigned short* DWB_x2high = FINAB + 4915200;     // 409600
    unsigned short* DWB_x2mid = FINAB + 5324800;      // 409600

    {
        DwP dp{};
        dp.xtb[0] = XTB0; dp.out[0] = DWB_x0mid;  dp.wdt[0] = DWT + 1 * 2304;
        dp.sc[0] = dw_s_m; dp.bi[0] = dw_b_m; dp.H[0] = 80; dp.W[0] = 80;
        dp.xtb[1] = XTB0; dp.out[1] = DWB_x0low;  dp.wdt[1] = DWT + 2 * 2304;
        dp.sc[1] = dw_s_l; dp.bi[1] = dw_b_l; dp.H[1] = 80; dp.W[1] = 80;
        dp.xtb[2] = XTB1; dp.out[2] = DWB_x1high; dp.wdt[2] = DWT + 0 * 2304;
        dp.sc[2] = dw_s_h; dp.bi[2] = dw_b_h; dp.H[2] = 40; dp.W[2] = 40;
        dp.xtb[3] = XTB1; dp.out[3] = DWB_x1mid;  dp.wdt[3] = DWT + 1 * 2304;
        dp.sc[3] = dw_s_m; dp.bi[3] = dw_b_m; dp.H[3] = 40; dp.W[3] = 40;
        dp.xtb[4] = XTB1; dp.out[4] = DWB_x1low;  dp.wdt[4] = DWT + 2 * 2304;
        dp.sc[4] = dw_s_l; dp.bi[4] = dw_b_l; dp.H[4] = 40; dp.W[4] = 40;
        dp.xtb[5] = XTB2; dp.out[5] = DWB_x2high; dp.wdt[5] = DWT + 0 * 2304;
        dp.sc[5] = dw_s_h; dp.bi[5] = dw_b_h; dp.H[5] = 20; dp.W[5] = 20;
        dp.xtb[6] = XTB2; dp.out[6] = DWB_x2mid;  dp.wdt[6] = DWT + 1 * 2304;
        dp.sc[6] = dw_s_m; dp.bi[6] = dw_b_m; dp.H[6] = 20; dp.W[6] = 20;
        dp.blk[0] = 0;    dp.blk[1] = 3200; dp.blk[2] = 6400; dp.blk[3] = 7200;
        dp.blk[4] = 8000; dp.blk[5] = 8800; dp.blk[6] = 9000; dp.blk[7] = 9200;
        k_dw_silu_b<<<9200, 256, 0, stream>>>(dp);
    }

    {   // unified offmask: 7 feats, 1 launch
        OmP7 op{};
        auto setf = [&](int i, const unsigned short* dwb, float* om, int Hs, int Ws,
                        int Wo, int HoWo, int ss, int ths, int tws, int SR, int SC,
                        int nz) {
            op.dwb[i] = dwb; op.om[i] = om;
            op.Hs[i] = Hs; op.Ws[i] = Ws; op.Wo[i] = Wo; op.HoWo[i] = HoWo;
            op.ss[i] = ss; op.ths[i] = ths; op.tws[i] = tws;
            op.SR[i] = SR; op.SC[i] = SC; op.Msc[i] = (65536 + SC - 1) / SC;
            op.nz[i] = nz; op.Mnz[i] = (65536 + nz - 1) / nz;
        };
        setf(0, DWB_x0mid,  OM_l0mid,  80, 80, 80, 6400, 0, 3, 3, 10, 10, 10);
        setf(1, DWB_x1high, OM_l0high, 40, 40, 40, 1600, 0, 2, 3, 6,  10, 5);
        setf(2, DWB_x1mid,  OM_l1mid,  40, 40, 40, 1600, 0, 2, 3, 6,  10, 5);
        setf(3, DWB_x0low,  OM_l1low,  80, 80, 40, 1600, 1, 2, 3, 9,  17, 5);
        setf(4, DWB_x2high, OM_l1high, 20, 20, 20, 400,  0, 2, 2, 6,  6,  5);
        setf(5, DWB_x2mid,  OM_l2mid,  20, 20, 20, 400,  0, 2, 2, 6,  6,  5);
        setf(6, DWB_x1low,  OM_l2low,  40, 40, 20, 400,  1, 2, 2, 9,  9,  5);
        op.blk[0] = 0;    op.blk[1] = 1600; op.blk[2] = 2400; op.blk[3] = 3200;
        op.blk[4] = 4000; op.blk[5] = 4400; op.blk[6] = 4800; op.blk[7] = 5200;
        k_offmask_b<<<5200, 256, 0, stream>>>(op, WMFB);
    }

    {
        SmP sp{};
        auto setf = [&](int i, const unsigned short* xtb, const float* om,
                        unsigned short* raw, int slot, int Hs, int Ws, int Wo, int HoWo,
                        int stride, int softmax, int up, const float* upt) {
            sp.xtb[i] = xtb; sp.om[i] = om; sp.raw[i] = raw;
            sp.stats[i] = STATS + slot * 128;
            sp.rsum[i] = REP + slot * 1024;
            sp.upt[i] = upt;
            sp.Hs[i] = Hs; sp.Ws[i] = Ws; sp.Wo[i] = Wo; sp.HoWo[i] = HoWo;
            sp.stride[i] = stride; sp.softmax[i] = softmax; sp.up[i] = up;
        };
        setf(0, XTB0, OM_l0mid,  RAW_l0mid,  0, 80, 80, 80, 6400, 1, 0, 0, UPW);
        setf(1, XTB1, OM_l0high, RAW_l0high, 1, 40, 40, 40, 1600, 1, 1, 1, UPW);
        setf(2, XTB1, OM_l1mid,  RAW_l1mid,  2, 40, 40, 40, 1600, 1, 0, 0, UPW);
        setf(3, XTB0, OM_l1low,  RAW_l1low,  3, 80, 80, 40, 1600, 2, 1, 0, UPW);
        setf(4, XTB2, OM_l1high, RAW_l1high, 4, 20, 20, 20, 400,  1, 1, 1, UPW + 40);
        setf(5, XTB2, OM_l2mid,  RAW_l2mid,  5, 20, 20, 20, 400,  1, 0, 0, UPW);
        setf(6, XTB1, OM_l2low,  RAW_l2low,  6, 40, 40, 20, 400,  2, 1, 0, UPW);
        sp.blk[0] = 0;    sp.blk[1] = 3200; sp.blk[2] = 4000; sp.blk[3] = 4800;
        sp.blk[4] = 5600; sp.blk[5] = 5800; sp.blk[6] = 6000; sp.blk[7] = 6200;
        k_sample_b<<<6200, 256, 0, stream>>>(sp, off_b);
    }

    {
        CfP cp{};
        cp.nf[0] = 2; cp.inv_nl[0] = 0.5f;      cp.inv_hw[0] = 1.f / 6400.f;
        cp.nf[1] = 3; cp.inv_nl[1] = 1.f / 3.f; cp.inv_hw[1] = 1.f / 1600.f;
        cp.nf[2] = 2; cp.inv_nl[2] = 0.5f;      cp.inv_hw[2] = 1.f / 400.f;
        cp.ft[0][0] = {REP + 0 * 1024, STATS + 0 * 128, gn_g_m, gn_b_m, 102400.f};
        cp.ft[0][1] = {REP + 1 * 1024, STATS + 1 * 128, gn_g_h, gn_b_h, 25600.f};
        cp.ft[1][0] = {REP + 2 * 1024, STATS + 2 * 128, gn_g_m, gn_b_m, 25600.f};
        cp.ft[1][1] = {REP + 3 * 1024, STATS + 3 * 128, gn_g_l, gn_b_l, 25600.f};
        cp.ft[1][2] = {REP + 4 * 1024, STATS + 4 * 128, gn_g_h, gn_b_h, 6400.f};
        cp.ft[2][0] = {REP + 5 * 1024, STATS + 5 * 128, gn_g_m, gn_b_m, 6400.f};
        cp.ft[2][1] = {REP + 6 * 1024, STATS + 6 * 128, gn_g_l, gn_b_l, 6400.f};
        k_coef_b<<<12, 256, 0, stream>>>(cp, sa_w, sa_b, fc1_w, fc1_b, fc2_w, fc2_b,
                                         COEF, AF);
    }

    {
        StP st{};
        st.out[0] = out0; st.nf[0] = 2; st.HW[0] = 6400; st.Wf[0] = 80; st.npt[0] = 100;
        st.out[1] = out1; st.nf[1] = 3; st.HW[1] = 1600; st.Wf[1] = 40; st.npt[1] = 25;
        st.out[2] = out2; st.nf[2] = 2; st.HW[2] = 400;  st.Wf[2] = 20; st.npt[2] = 7;
        st.ft[0][0] = {RAW_l0mid,  STATS + 0 * 128, gn_g_m, gn_b_m, 102400.f, 0, 80, 80, 1.f, 1.f};
        st.ft[0][1] = {RAW_l0high, STATS + 1 * 128, gn_g_h, gn_b_h, 25600.f,  1, 40, 40, SYS_L0H, SYS_L0H};
        st.ft[1][0] = {RAW_l1mid,  STATS + 2 * 128, gn_g_m, gn_b_m, 25600.f,  0, 40, 40, 1.f, 1.f};
        st.ft[1][1] = {RAW_l1low,  STATS + 3 * 128, gn_g_l, gn_b_l, 25600.f,  0, 40, 40, 1.f, 1.f};
        st.ft[1][2] = {RAW_l1high, STATS + 4 * 128, gn_g_h, gn_b_h, 6400.f,   1, 20, 20, SYS_L1H, SYS_L1H};
        st.ft[2][0] = {RAW_l2mid,  STATS + 5 * 128, gn_g_m, gn_b_m, 6400.f,   0, 20, 20, 1.f, 1.f};
        st.ft[2][1] = {RAW_l2low,  STATS + 6 * 128, gn_g_l, gn_b_l, 6400.f,   0, 20, 20, 1.f, 1.f};
        st.blk[0] = 0; st.blk[1] = 1600; st.blk[2] = 2000; st.blk[3] = 2112;
        k_store_b<<<2112, 256, 0, stream>>>(st, COEF, AF);
    }
}

// Round 10
// 353.728 us; speedup vs baseline: 1.0301x; 1.0072x over previous
//
#include <hip/hip_runtime.h>
#include <hip/hip_bf16.h>

#define C_ 256
#define G_ 4

typedef __attribute__((ext_vector_type(8))) short bf16x8;
typedef __attribute__((ext_vector_type(4))) float f32x4;

static __device__ __forceinline__ unsigned short f2bf(float x) {
    __hip_bfloat16 h = __float2bfloat16(x);
    return *(unsigned short*)&h;
}
static __device__ __forceinline__ float bf2f(unsigned short u) {
    return __uint_as_float((unsigned)u << 16);
}
static __device__ __forceinline__ float4 bf4(ushort4 u) {
    float4 r;
    r.x = bf2f(u.x);
    r.y = bf2f(u.y);
    r.z = bf2f(u.z);
    r.w = bf2f(u.w);
    return r;
}

// total bilinear weight that source row y receives across all Hf output rows;
// mirrors the store interp exactly (trunc coords, y1 = min(y0+1, Hr-1) clamp).
static __device__ __forceinline__ float upw(int y, int Hr, int Hf, float sys) {
    float inv = 1.f / sys;
    int lo = max(0, (int)((y - 1) * inv) - 1);
    int hi = min(Hf - 1, (int)((y + 1) * inv) + 1);
    float w = 0.f;
    for (int o = lo; o <= hi; o++) {
        float sy = o * sys;
        int y0 = (int)sy;
        float fy = sy - y0;
        int y1 = min(y0 + 1, Hr - 1);
        if (y0 == y) w += 1.f - fy;
        if (y1 == y) w += fy;
    }
    return w;
}

// ---------------------------------------------------------------- prep ----
__global__ void k_prep(const float* __restrict__ off_w, const float* __restrict__ dwh,
                       const float* __restrict__ dwm, const float* __restrict__ dwl,
                       unsigned short* __restrict__ wmf, float* __restrict__ dwt,
                       float* __restrict__ zeros, float* __restrict__ rep,
                       float* __restrict__ upwt) {
    int i = blockIdx.x * 256 + threadIdx.x;
    const int NWM = 4 * 32 * 576;
    if (i < NWM) {
        int g = i / (32 * 576), rem = i % (32 * 576);
        int ol = rem / 576, kk = rem % 576;
        int tap = kk / 64, ic = kk % 64;
        float v = (ol < 27) ? off_w[((size_t)((g * 27 + ol) * 64 + ic)) * 9 + tap] : 0.f;
        wmf[i] = f2bf(v);
    }
    int j = i - NWM;
    if (j >= 0 && j < 3 * 2304) {
        int which = j / 2304, rem = j % 2304;
        int t = rem / 256, c = rem % 256;
        const float* src = (which == 0) ? dwh : (which == 1) ? dwm : dwl;
        dwt[j] = src[c * 9 + t];
    }
    int z = i - NWM - 3 * 2304;
    if (z >= 0 && z < 896) zeros[z] = 0.f;
    int z2 = z - 896;
    if (z2 >= 0 && z2 < 4 * 7168) rep[z2] = 0.f;
    int z3 = z2 - 4 * 7168;
    if (z3 >= 0 && z3 < 64) {
        float w = 0.f;
        if (z3 < 40) w = upw(z3, 40, 80, (float)(39.0 / 79.0));
        else if (z3 < 60) w = upw(z3 - 40, 20, 40, (float)(19.0 / 39.0));
        upwt[z3] = w;
    }
}

// ------------------------------------------------- batched transpose (3 srcs) ----
struct TrP {
    const float* x[3];
    unsigned short* xtb[3];
    int H[3];
    int W[3];
    int wtc[3];
    int blk[4];
};

__global__ __launch_bounds__(256) void k_transpose_b(TrP P) {
    __shared__ float tile[32][33];
    int b = blockIdx.x;
    int f = (b >= P.blk[1]) + (b >= P.blk[2]);
    int l = b - P.blk[f];
    int H = P.H[f], W = P.W[f], wtc = P.wtc[f];
    int nh = l / wtc, wtile = l - nh * wtc;
    int n = nh / H, h = nh % H;
    int w0 = wtile * 32, c0 = blockIdx.y * 32;
    const float* x = P.x[f];
    unsigned short* xtb = P.xtb[f];
    int tid = threadIdx.x;
    int i = tid / 32, j = tid % 32;
#pragma unroll
    for (int r = 0; r < 4; r++) {
        int c = c0 + i + r * 8;
        int w = w0 + j;
        tile[i + r * 8][j] = (w < W) ? x[((size_t)(n * C_ + c) * H + h) * W + w] : 0.f;
    }
    __syncthreads();
    int wj = tid >> 4, ci2 = (tid & 15) * 2;
#pragma unroll
    for (int r = 0; r < 2; r++) {
        int w = w0 + wj + r * 16;
        if (w < W) {
            ushort2 o;
            o.x = f2bf(tile[ci2][wj + r * 16]);
            o.y = f2bf(tile[ci2 + 1][wj + r * 16]);
            *(ushort2*)(xtb + ((size_t)(n * H + h) * W + w) * C_ + c0 + ci2) = o;
        }
    }
}

// ------------------- batched depthwise+SiLU (7 feats, ushort8 lane-split) ----
struct DwP {
    const unsigned short* xtb[7];
    unsigned short* out[7];
    const float* wdt[7];
    const float* sc[7];
    const float* bi[7];
    int H[7];
    int W[7];
    int blk[8];
};

__global__ __launch_bounds__(256) void k_dw_silu_b(DwP P) {
    int b = blockIdx.x;
    int f = (b >= P.blk[1]) + (b >= P.blk[2]) + (b >= P.blk[3]) + (b >= P.blk[4]) +
            (b >= P.blk[5]) + (b >= P.blk[6]);
    int H = P.H[f], W = P.W[f];
    const unsigned short* xtbf = P.xtb[f];
    unsigned short* outf = P.out[f];
    const float* wdt = P.wdt[f];
    int tid = threadIdx.x;
    int wv = tid >> 6, lane = tid & 63;
    int half = lane >> 5, l5 = lane & 31;
    int ch8 = l5 << 3;
    int pix = (b - P.blk[f]) * 8 + wv * 2 + half;
    int w = pix % W, h = (pix / W) % H, n = pix / (W * H);
    const float4 sA = *(const float4*)(P.sc[f] + ch8);
    const float4 sB = *(const float4*)(P.sc[f] + ch8 + 4);
    const float4 bA = *(const float4*)(P.bi[f] + ch8);
    const float4 bB = *(const float4*)(P.bi[f] + ch8 + 4);
    const unsigned short* xb = xtbf + (size_t)n * H * W * C_ + ch8;
    float4 accA = {0.f, 0.f, 0.f, 0.f}, accB = {0.f, 0.f, 0.f, 0.f};
#pragma unroll
    for (int t = 0; t < 9; t++) {
        int hh = h + t / 3 - 1, ww = w + t % 3 - 1;
        if (hh >= 0 && hh < H && ww >= 0 && ww < W) {
            bf16x8 xv = *(const bf16x8*)(xb + (size_t)(hh * W + ww) * C_);
            float4 wa = *(const float4*)(wdt + t * 256 + ch8);
            float4 wb = *(const float4*)(wdt + t * 256 + ch8 + 4);
            accA.x += wa.x * bf2f((unsigned short)xv[0]);
            accA.y += wa.y * bf2f((unsigned short)xv[1]);
            accA.z += wa.z * bf2f((unsigned short)xv[2]);
            accA.w += wa.w * bf2f((unsigned short)xv[3]);
            accB.x += wb.x * bf2f((unsigned short)xv[4]);
            accB.y += wb.y * bf2f((unsigned short)xv[5]);
            accB.z += wb.z * bf2f((unsigned short)xv[6]);
            accB.w += wb.w * bf2f((unsigned short)xv[7]);
        }
    }
    float y0 = accA.x * sA.x + bA.x, y1 = accA.y * sA.y + bA.y;
    float y2 = accA.z * sA.z + bA.z, y3 = accA.w * sA.w + bA.w;
    float y4 = accB.x * sB.x + bB.x, y5 = accB.y * sB.y + bB.y;
    float y6 = accB.z * sB.z + bB.z, y7 = accB.w * sB.w + bB.w;
    y0 = y0 / (1.f + __expf(-y0));
    y1 = y1 / (1.f + __expf(-y1));
    y2 = y2 / (1.f + __expf(-y2));
    y3 = y3 / (1.f + __expf(-y3));
    y4 = y4 / (1.f + __expf(-y4));
    y5 = y5 / (1.f + __expf(-y5));
    y6 = y6 / (1.f + __expf(-y6));
    y7 = y7 / (1.f + __expf(-y7));
    uint4 ov;
    ov.x = (unsigned)f2bf(y0) | ((unsigned)f2bf(y1) << 16);
    ov.y = (unsigned)f2bf(y2) | ((unsigned)f2bf(y3) << 16);
    ov.z = (unsigned)f2bf(y4) | ((unsigned)f2bf(y5) << 16);
    ov.w = (unsigned)f2bf(y6) | ((unsigned)f2bf(y7) << 16);
    *(uint4*)(outf + (size_t)pix * C_ + ch8) = ov;
}

// -------------------- unified grouped offset/mask conv (7 feats, 1 launch) ----
struct OmP7 {
    const unsigned short* dwb[7];
    float* om[7];
    int Hs[7], Ws[7], Wo[7], HoWo[7];
    int ss[7];
    int ths[7], tws[7];
    int SR[7], SC[7], Msc[7];
    int nz[7], Mnz[7];
    int blk[8];
};

__global__ __launch_bounds__(256) void k_offmask_b(OmP7 P,
                                                   const unsigned short* __restrict__ wmf) {
    __shared__ __align__(16) char smem[22032];
    unsigned short* patch = (unsigned short*)smem;
    float* omv = (float*)smem;

    int tid = threadIdx.x;
    int wv = tid >> 6, lane = tid & 63;
    int n16 = lane & 15, q = lane >> 4;
    int b = blockIdx.x;
    int f = (b >= P.blk[1]) + (b >= P.blk[2]) + (b >= P.blk[3]) + (b >= P.blk[4]) +
            (b >= P.blk[5]) + (b >= P.blk[6]);
    int l = b - P.blk[f];
    int n = (l >> 2) & 3, g = l & 3;
    int tile = l >> 4;
    int nz = P.nz[f];
    int ty = (tile * P.Mnz[f]) >> 16;
    int tz = tile - ty * nz;
    int ss = P.ss[f], ths = P.ths[f], tws = P.tws[f];
    int TW = 1 << tws;
    int SR = P.SR[f], SC = P.SC[f], Msc = P.Msc[f];
    int NV = SR * SC;
    int Hs = P.Hs[f], Ws = P.Ws[f], Wo = P.Wo[f], HoWo = P.HoWo[f];
    int ho0 = ty << ths, wo0 = tz << tws;
    int hs0 = (ho0 << ss) - 1, ws0 = (wo0 << ss) - 1;
    const unsigned short* dwb = P.dwb[f];
    float* om = P.om[f];

    for (int idx = tid; idx < NV * 8; idx += 256) {
        int pp = idx >> 3;
        int c8 = (idx & 7) << 3;
        int pq = (pp * Msc) >> 16;
        int hh = hs0 + pq, ww = ws0 + (pp - pq * SC);
        uint4 v = {0u, 0u, 0u, 0u};
        if (hh >= 0 && hh < Hs && ww >= 0 && ww < Ws)
            v = *(const uint4*)(dwb + ((size_t)(n * Hs + hh) * Ws + ww) * C_ + g * 64 + c8);
        *(uint4*)(patch + pp * 72 + c8) = v;
    }
    __syncthreads();

    int bchan = q << 3;
    const unsigned short* wg = wmf + (size_t)g * 32 * 576;
    int TP = 1 << (ths + tws);
    int sc1 = SC, sc2 = SC * 2;

    if (TP == 64) {
        int p = wv * 16 + n16;
        int pr = p >> tws, pc = p & (TW - 1);
        int pixbase = (pr << ss) * SC + (pc << ss);
        f32x4 a0 = {0.f, 0.f, 0.f, 0.f}, a1 = {0.f, 0.f, 0.f, 0.f};
#pragma unroll
        for (int kk = 0; kk < 18; kk++) {
            int tap = kk >> 1;
            int ic0 = (kk & 1) << 5;
            int tr = tap / 3, tc = tap % 3;
            int ppix = pixbase + (tr == 0 ? 0 : (tr == 1 ? sc1 : sc2)) + tc;
            bf16x8 bb = *(const bf16x8*)(patch + ppix * 72 + ic0 + bchan);
            bf16x8 wa0 = *(const bf16x8*)(wg + (size_t)n16 * 576 + kk * 32 + bchan);
            bf16x8 wa1 = *(const bf16x8*)(wg + (size_t)(16 + n16) * 576 + kk * 32 + bchan);
            a0 = __builtin_amdgcn_mfma_f32_16x16x32_bf16(wa0, bb, a0, 0, 0, 0);
            a1 = __builtin_amdgcn_mfma_f32_16x16x32_bf16(wa1, bb, a1, 0, 0, 0);
        }
        __syncthreads();
#pragma unroll
        for (int r = 0; r < 4; r++) {
            int ol0 = q * 4 + r;
            omv[p * 28 + ol0] = a0[r];
            int ol1 = 16 + q * 4 + r;
            if (ol1 < 28) omv[p * 28 + ol1] = a1[r];
        }
    } else {
        int NT = TP >> 3;
        int t = wv;
        bool active = t < NT;
        int ntile = t >> 1, mtile = t & 1;
        int p = ntile * 16 + n16;
        int pr = p >> tws, pc = p & (TW - 1);
        int pixbase = (pr << ss) * SC + (pc << ss);
        f32x4 acc = {0.f, 0.f, 0.f, 0.f};
        if (active) {
#pragma unroll
            for (int kk = 0; kk < 18; kk++) {
                int tap = kk >> 1;
                int ic0 = (kk & 1) << 5;
                int tr = tap / 3, tc = tap % 3;
                int ppix = pixbase + (tr == 0 ? 0 : (tr == 1 ? sc1 : sc2)) + tc;
                bf16x8 bb = *(const bf16x8*)(patch + ppix * 72 + ic0 + bchan);
                bf16x8 wa = *(const bf16x8*)(wg + (size_t)(mtile * 16 + n16) * 576 +
                                             kk * 32 + bchan);
                acc = __builtin_amdgcn_mfma_f32_16x16x32_bf16(wa, bb, acc, 0, 0, 0);
            }
        }
        __syncthreads();
        if (active) {
#pragma unroll
            for (int r = 0; r < 4; r++) {
                int ol = mtile * 16 + q * 4 + r;
                if (ol < 28) omv[p * 28 + ol] = acc[r];
            }
        }
    }
    __syncthreads();

    float* omg = om + ((size_t)(g * 4 + n)) * HoWo * 28;
    for (int idx = tid; idx < TP * 7; idx += 256) {
        int p = (idx * 9363) >> 16;
        int c4 = idx - p * 7;
        int ho = ho0 + (p >> tws), wo = wo0 + (p & (TW - 1));
        int pixn = ho * Wo + wo;
        *(float4*)(omg + (size_t)pixn * 28 + c4 * 4) = *(float4*)(omv + p * 28 + c4 * 4);
    }
}

// -------------- batched DCNv3 sample (7 feats) + per-channel weighted sums ----
// r7-proven reduction (lsum[8][256] + per-thread weighted sum); wup via table.
struct SmP {
    const unsigned short* xtb[7];
    const float* om[7];
    unsigned short* raw[7];
    float* stats[7];
    float* rsum[7];   // replica-0 base; replica stride 7168 floats
    const float* upt[7];
    int Hs[7];
    int Ws[7];
    int Wo[7];
    int HoWo[7];
    int stride[7];
    int softmax[7];
    int up[7];
    int blk[8];
};

__global__ __launch_bounds__(256) void k_sample_b(SmP P, const float* __restrict__ bias) {
    int tid = threadIdx.x;
    int wv = tid >> 6, lane = tid & 63;
    int halfp = lane >> 5, l5 = lane & 31;
    int g = l5 >> 3;
    int ch8 = l5 << 3;
    int nb = gridDim.x;
    int per = nb >> 3, rem = nb & 7;
    int xcd = blockIdx.x & 7, bi = blockIdx.x >> 3;
    int logical = xcd * per + min(xcd, rem) + bi;
    int f = (logical >= P.blk[1]) + (logical >= P.blk[2]) + (logical >= P.blk[3]) +
            (logical >= P.blk[4]) + (logical >= P.blk[5]) + (logical >= P.blk[6]);
    const unsigned short* xtb = P.xtb[f];
    const float* om = P.om[f];
    unsigned short* raw = P.raw[f];
    float* stats = P.stats[f];
    float* rsum = P.rsum[f] + (blockIdx.x & 3) * 7168;
    int Hs = P.Hs[f], Ws = P.Ws[f], Wo = P.Wo[f], HoWo = P.HoWo[f];
    int stride = P.stride[f], softmax = P.softmax[f];
    int upf = P.up[f];
    int pix0 = (logical - P.blk[f]) * 8;
    int n = pix0 / HoWo;
    int pixn0 = pix0 - n * HoWo;

    __shared__ float lom[8 * 112];
    __shared__ float lb[108];
    __shared__ float sm[32][9];
    __shared__ float4 lw[288];
    __shared__ ushort4 li[288];
    __shared__ float lstat[32];
    __shared__ float lsum[8][256];
    __shared__ float wup[8];

    // stage OM: 4 group chunks x 8 pixels x 28 floats
    if (tid < 224) {
        int gc = tid / 56, r2 = tid % 56;
        int pp = r2 / 7, c4 = r2 % 7;
        float4 v = *(const float4*)(om + ((size_t)(gc * 4 + n) * HoWo + pixn0 + pp) * 28 +
                                    c4 * 4);
        ((float4*)lom)[pp * 28 + gc * 7 + c4] = v;
    }
    if (tid < 108) lb[tid] = bias[tid];
    if (tid < 32) lstat[tid] = 0.f;
    __syncthreads();

    // masks (softmax / sigmoid) per (pixel, sampling group)
    if (tid < 32) {
        int pp = tid >> 2, gs = tid & 3;
        float mv[9];
#pragma unroll
        for (int k = 0; k < 9; k++) {
            int ch = 72 + gs * 9 + k;
            int gc = ch / 27;
            mv[k] = lom[pp * 112 + gc * 28 + (ch - gc * 27)] + lb[ch];
        }
        if (softmax) {
            float mx = -1e30f;
#pragma unroll
            for (int k = 0; k < 9; k++) mx = fmaxf(mx, mv[k]);
            float ssum = 0.f;
#pragma unroll
            for (int k = 0; k < 9; k++) {
                mv[k] = __expf(mv[k] - mx);
                ssum += mv[k];
            }
            float inv = 1.f / ssum;
#pragma unroll
            for (int k = 0; k < 9; k++) sm[tid][k] = mv[k] * inv;
        } else {
#pragma unroll
            for (int k = 0; k < 9; k++) sm[tid][k] = 1.f / (1.f + __expf(-mv[k]));
        }
    }
    // per-pixel upsample total weight (1 for native feats; table lookup)
    if (tid < 8) {
        float w = 1.f;
        if (upf) {
            int pixn = pixn0 + tid;
            int ho = pixn / Wo, wo = pixn - ho * Wo;
            const float* t = P.upt[f];
            w = t[ho] * t[wo];
        }
        wup[tid] = w;
    }
    __syncthreads();

    // bilinear weights + clamped indices per (pixel, group, tap)
    for (int idx = tid; idx < 288; idx += 256) {
        int pg = idx / 9, k = idx % 9;
        int pp = pg >> 2, gs = pg & 3;
        int chy = gs * 18 + 2 * k, chx = chy + 1;
        int gcy = chy / 27, gcx = chx / 27;
        float oy = lom[pp * 112 + gcy * 28 + (chy - gcy * 27)] + lb[chy];
        float ox = lom[pp * 112 + gcx * 28 + (chx - gcx * 27)] + lb[chx];
        int pixn = pixn0 + pp;
        int ho = pixn / Wo, wo = pixn % Wo;
        float py = (float)(ho * stride + k / 3 - 1) + oy;
        float px = (float)(wo * stride + k % 3 - 1) + ox;
        float y0f = floorf(py), x0f = floorf(px);
        int y0 = (int)y0f, x0 = (int)x0f;
        float wy = py - y0f, wx = px - x0f;
        int y1 = y0 + 1, x1 = x0 + 1;
        float v0y = (y0 >= 0 && y0 < Hs) ? 1.f : 0.f;
        float v1y = (y1 >= 0 && y1 < Hs) ? 1.f : 0.f;
        float v0x = (x0 >= 0 && x0 < Ws) ? 1.f : 0.f;
        float v1x = (x1 >= 0 && x1 < Ws) ? 1.f : 0.f;
        int y0c = min(max(y0, 0), Hs - 1), y1c = min(max(y1, 0), Hs - 1);
        int x0c = min(max(x0, 0), Ws - 1), x1c = min(max(x1, 0), Ws - 1);
        float m_ = sm[pg][k];
        float4 w4;
        w4.x = (1.f - wy) * (1.f - wx) * v0y * v0x * m_;
        w4.y = (1.f - wy) * wx * v0y * v1x * m_;
        w4.z = wy * (1.f - wx) * v1y * v0x * m_;
        w4.w = wy * wx * v1y * v1x * m_;
        ushort4 i4;
        i4.x = (unsigned short)(y0c * Ws + x0c);
        i4.y = (unsigned short)(y0c * Ws + x1c);
        i4.z = (unsigned short)(y1c * Ws + x0c);
        i4.w = (unsigned short)(y1c * Ws + x1c);
        lw[pp * 36 + gs * 9 + k] = w4;
        li[pp * 36 + gs * 9 + k] = i4;
    }
    __syncthreads();

    int px = wv * 2 + halfp;
    const unsigned short* xb = xtb + (size_t)n * Hs * Ws * C_ + ch8;
    float4 aL = {0.f, 0.f, 0.f, 0.f}, aH = {0.f, 0.f, 0.f, 0.f};
#pragma unroll
    for (int k = 0; k < 9; k++) {
        float4 w4 = lw[px * 36 + g * 9 + k];
        ushort4 i4 = li[px * 36 + g * 9 + k];
        bf16x8 v0 = *(const bf16x8*)(xb + ((size_t)i4.x << 8));
        bf16x8 v1 = *(const bf16x8*)(xb + ((size_t)i4.y << 8));
        bf16x8 v2 = *(const bf16x8*)(xb + ((size_t)i4.z << 8));
        bf16x8 v3 = *(const bf16x8*)(xb + ((size_t)i4.w << 8));
        aL.x += w4.x * bf2f((unsigned short)v0[0]) + w4.y * bf2f((unsigned short)v1[0]) +
                w4.z * bf2f((unsigned short)v2[0]) + w4.w * bf2f((unsigned short)v3[0]);
        aL.y += w4.x * bf2f((unsigned short)v0[1]) + w4.y * bf2f((unsigned short)v1[1]) +
                w4.z * bf2f((unsigned short)v2[1]) + w4.w * bf2f((unsigned short)v3[1]);
        aL.z += w4.x * bf2f((unsigned short)v0[2]) + w4.y * bf2f((unsigned short)v1[2]) +
                w4.z * bf2f((unsigned short)v2[2]) + w4.w * bf2f((unsigned short)v3[2]);
        aL.w += w4.x * bf2f((unsigned short)v0[3]) + w4.y * bf2f((unsigned short)v1[3]) +
                w4.z * bf2f((unsigned short)v2[3]) + w4.w * bf2f((unsigned short)v3[3]);
        aH.x += w4.x * bf2f((unsigned short)v0[4]) + w4.y * bf2f((unsigned short)v1[4]) +
                w4.z * bf2f((unsigned short)v2[4]) + w4.w * bf2f((unsigned short)v3[4]);
        aH.y += w4.x * bf2f((unsigned short)v0[5]) + w4.y * bf2f((unsigned short)v1[5]) +
                w4.z * bf2f((unsigned short)v2[5]) + w4.w * bf2f((unsigned short)v3[5]);
        aH.z += w4.x * bf2f((unsigned short)v0[6]) + w4.y * bf2f((unsigned short)v1[6]) +
                w4.z * bf2f((unsigned short)v2[6]) + w4.w * bf2f((unsigned short)v3[6]);
        aH.w += w4.x * bf2f((unsigned short)v0[7]) + w4.y * bf2f((unsigned short)v1[7]) +
                w4.z * bf2f((unsigned short)v2[7]) + w4.w * bf2f((unsigned short)v3[7]);
    }
    uint4 ov;
    ov.x = (unsigned)f2bf(aL.x) | ((unsigned)f2bf(aL.y) << 16);
    ov.y = (unsigned)f2bf(aL.z) | ((unsigned)f2bf(aL.w) << 16);
    ov.z = (unsigned)f2bf(aH.x) | ((unsigned)f2bf(aH.y) << 16);
    ov.w = (unsigned)f2bf(aH.z) | ((unsigned)f2bf(aH.w) << 16);
    *(uint4*)(raw + (size_t)(pix0 + px) * C_ + ch8) = ov;
    *(float4*)&lsum[px][ch8] = aL;
    *(float4*)&lsum[px][ch8 + 4] = aH;
    float gs = aL.x + aL.y + aL.z + aL.w + aH.x + aH.y + aH.z + aH.w;
    float gss = aL.x * aL.x + aL.y * aL.y + aL.z * aL.z + aL.w * aL.w + aH.x * aH.x +
                aH.y * aH.y + aH.z * aH.z + aH.w * aH.w;
    gs += __shfl_down(gs, 1, 2);
    gss += __shfl_down(gss, 1, 2);
    if ((lane & 1) == 0) {
        atomicAdd(&lstat[(l5 >> 1) * 2 + 0], gs);
        atomicAdd(&lstat[(l5 >> 1) * 2 + 1], gss);
    }
    __syncthreads();
    if (tid < 32) atomicAdd(&stats[n * 32 + tid], lstat[tid]);
    // weighted per-channel sums (for analytic GN channel-means)
    {
        float s = 0.f;
#pragma unroll
        for (int p2 = 0; p2 < 8; p2++) s += wup[p2] * lsum[p2][tid];
        atomicAdd(&rsum[n * 256 + tid], s);
    }
}

// ------------------- batched per-(level,n) scale-attn + DyReLU coefficients ----
struct CfF {
    const float* rsum;  // replica-0 base; sum 4 replicas stride 7168
    const float* stats;
    const float* gamma;
    const float* beta;
    float cnt;
};
struct CfP {
    CfF ft[3][3];
    int nf[3];
    float inv_nl[3];
    float inv_hw[3];
};

__global__ __launch_bounds__(256) void k_coef_b(CfP P,
                                                const float* __restrict__ sa_w,
                                                const float* __restrict__ sa_b,
                                                const float* __restrict__ fc1_w,
                                                const float* __restrict__ fc1_b,
                                                const float* __restrict__ fc2_w,
                                                const float* __restrict__ fc2_b,
                                                float* __restrict__ coef,
                                                float* __restrict__ af) {
    int lvl = blockIdx.x >> 2;
    int n = blockIdx.x & 3;
    int nf = P.nf[lvl];
    float inv_nl = P.inv_nl[lvl], inv_hw = P.inv_hw[lvl];
    int c = threadIdx.x;
    __shared__ float red[256];
    __shared__ __align__(16) float meanv[256];
    __shared__ __align__(16) float hv[64];
    __shared__ float sa_a[3];
    float cm[3] = {0.f, 0.f, 0.f};
    int gg = c >> 4;
    for (int f = 0; f < nf; f++) {
        CfF s = P.ft[lvl][f];
        float s1 = s.stats[(n * 16 + gg) * 2], s2 = s.stats[(n * 16 + gg) * 2 + 1];
        float mu = s1 / s.cnt;
        float var = s2 / s.cnt - mu * mu;
        float rs = rsqrtf(var + 1e-5f);
        float ga = s.gamma[c] * rs;
        float be = s.beta[c] - mu * ga;
        float wsum = s.rsum[0 * 7168 + n * 256 + c] + s.rsum[1 * 7168 + n * 256 + c] +
                     s.rsum[2 * 7168 + n * 256 + c] + s.rsum[3 * 7168 + n * 256 + c];
        cm[f] = ga * wsum * inv_hw + be;
        red[c] = sa_w[c] * cm[f];
        __syncthreads();
        for (int st = 128; st; st >>= 1) {
            if (c < st) red[c] += red[c + st];
            __syncthreads();
        }
        if (c == 0) {
            float t = fmaxf(red[0] + sa_b[0], 0.f);
            sa_a[f] = fminf(fmaxf((t + 3.f) * (1.f / 6.f), 0.f), 1.f);
        }
        __syncthreads();
    }
    float mv = 0.f;
    for (int f = 0; f < nf; f++) mv += sa_a[f] * cm[f];
    mv *= inv_nl;
    meanv[c] = mv;
    __syncthreads();
    int j = c >> 2, t = c & 3;
    float partial = 0.f;
    {
        const float4* fw = (const float4*)(fc1_w + j * 256 + t * 64);
        const float4* mv4 = (const float4*)(meanv + t * 64);
#pragma unroll
        for (int kk = 0; kk < 16; kk++) {
            float4 a = fw[kk], bb = mv4[kk];
            partial += a.x * bb.x + a.y * bb.y + a.z * bb.z + a.w * bb.w;
        }
    }
    partial += __shfl_down(partial, 2, 4);
    partial += __shfl_down(partial, 1, 4);
    if (t == 0) hv[j] = fmaxf(partial + fc1_b[j], 0.f);
    __syncthreads();
    float zz[4];
#pragma unroll
    for (int i = 0; i < 4; i++) {
        float z = fc2_b[i * 256 + c];
        const float4* f2 = (const float4*)(fc2_w + (size_t)(i * 256 + c) * 64);
        const float4* h4 = (const float4*)hv;
#pragma unroll
        for (int kk = 0; kk < 16; kk++) {
            float4 a = f2[kk], bb = h4[kk];
            z += a.x * bb.x + a.y * bb.y + a.z * bb.z + a.w * bb.w;
        }
        zz[i] = fminf(fmaxf(z + 3.f, 0.f), 6.f) * (1.f / 6.f);
    }
    float* cf = coef + lvl * 4096;
    cf[n * 1024 + 0 * 256 + c] = (zz[0] - 0.5f) * 2.f + 1.f;
    cf[n * 1024 + 1 * 256 + c] = zz[1] - 0.5f;
    cf[n * 1024 + 2 * 256 + c] = (zz[2] - 0.5f) * 2.f;
    cf[n * 1024 + 3 * 256 + c] = zz[3] - 0.5f;
    if (c < 4) af[lvl * 16 + n * 4 + c] = (c < nf) ? sa_a[c] * inv_nl : 0.f;
}

// -------- fused GN affine (+bilinear up) + combine + DyReLU + NCHW store ----
struct StF {
    const unsigned short* raw;  // bf16
    const float* stats;
    const float* gamma;
    const float* beta;
    float cnt;
    int up;
    int Hr;
    int Wr;
    float sys;
    float sxs;
};
struct StP {
    StF ft[3][3];
    float* out[3];
    int nf[3];
    int HW[3];
    int Wf[3];
    int npt[3];
    int blk[4];
};

__global__ __launch_bounds__(256) void k_store_b(StP P, const float* __restrict__ coef,
                                                 const float* __restrict__ af) {
    __shared__ float tile[64][65];
    int b = blockIdx.x;
    int f = (b >= P.blk[1]) + (b >= P.blk[2]);
    int l = b - P.blk[f];
    int npt = P.npt[f], HW = P.HW[f], Wf = P.Wf[f], nf = P.nf[f];
    int n = l / (npt * 4);
    int r_ = l - n * (npt * 4);
    int pt = r_ >> 2;
    int c0 = (r_ & 3) * 64;
    float* out = P.out[f];
    const float* coefL = coef + f * 4096;
    const float* afL = af + f * 16;
    int tid = threadIdx.x;
    int lane16 = tid & 15, prow = tid >> 4;
    int ch4 = c0 + lane16 * 4;
    int gg = ch4 >> 4;
    float a0 = afL[n * 4 + 0], a1f = afL[n * 4 + 1], a2f = afL[n * 4 + 2];
    float4 ca1 = *(const float4*)(coefL + n * 1024 + 0 + ch4);
    float4 cb1 = *(const float4*)(coefL + n * 1024 + 256 + ch4);
    float4 ca2 = *(const float4*)(coefL + n * 1024 + 512 + ch4);
    float4 cb2 = *(const float4*)(coefL + n * 1024 + 768 + ch4);

    StF sA = P.ft[f][0], sB = P.ft[f][1], sC = P.ft[f][2];
    auto mkgb = [&](const StF& s, float4& ga, float4& be) {
        float s1 = s.stats[(n * 16 + gg) * 2], s2 = s.stats[(n * 16 + gg) * 2 + 1];
        float mu = s1 / s.cnt;
        float var = s2 / s.cnt - mu * mu;
        float rs = rsqrtf(var + 1e-5f);
        float4 gm = *(const float4*)(s.gamma + ch4);
        float4 bt = *(const float4*)(s.beta + ch4);
        ga.x = gm.x * rs; be.x = bt.x - mu * ga.x;
        ga.y = gm.y * rs; be.y = bt.y - mu * ga.y;
        ga.z = gm.z * rs; be.z = bt.z - mu * ga.z;
        ga.w = gm.w * rs; be.w = bt.w - mu * ga.w;
    };
    float4 gaA, beA, gaB, beB, gaC = {0, 0, 0, 0}, beC = {0, 0, 0, 0};
    mkgb(sA, gaA, beA);
    mkgb(sB, gaB, beB);
    if (nf > 2) mkgb(sC, gaC, beC);

    auto rdf = [&](const StF& s, int p) -> float4 {
        if (!s.up)
            return bf4(*(const ushort4*)(s.raw + ((size_t)n * HW + p) * C_ + ch4));
        int ho = p / Wf, wo = p - ho * Wf;
        float sy = ho * s.sys, sx = wo * s.sxs;
        int y0 = (int)sy, x0 = (int)sx;
        float fy = sy - y0, fx = sx - x0;
        int y1 = min(y0 + 1, s.Hr - 1), x1 = min(x0 + 1, s.Wr - 1);
        const unsigned short* rb = s.raw + (size_t)n * s.Hr * s.Wr * C_ + ch4;
        float4 v00 = bf4(*(const ushort4*)(rb + (size_t)(y0 * s.Wr + x0) * C_));
        float4 v01 = bf4(*(const ushort4*)(rb + (size_t)(y0 * s.Wr + x1) * C_));
        float4 v10 = bf4(*(const ushort4*)(rb + (size_t)(y1 * s.Wr + x0) * C_));
        float4 v11 = bf4(*(const ushort4*)(rb + (size_t)(y1 * s.Wr + x1) * C_));
        float4 v;
        v.x = (v00.x * (1.f - fy) + v10.x * fy) * (1.f - fx) + (v01.x * (1.f - fy) + v11.x * fy) * fx;
        v.y = (v00.y * (1.f - fy) + v10.y * fy) * (1.f - fx) + (v01.y * (1.f - fy) + v11.y * fy) * fx;
        v.z = (v00.z * (1.f - fy) + v10.z * fy) * (1.f - fx) + (v01.z * (1.f - fy) + v11.z * fy) * fx;
        v.w = (v00.w * (1.f - fy) + v10.w * fy) * (1.f - fx) + (v01.w * (1.f - fy) + v11.w * fy) * fx;
        return v;
    };

#pragma unroll
    for (int pass = 0; pass < 4; pass++) {
        int px = pass * 16 + prow;
        int p = pt * 64 + px;
        if (p < HW) {
            float4 vA = rdf(sA, p);
            float4 fv;
            fv.x = (vA.x * gaA.x + beA.x) * a0;
            fv.y = (vA.y * gaA.y + beA.y) * a0;
            fv.z = (vA.z * gaA.z + beA.z) * a0;
            fv.w = (vA.w * gaA.w + beA.w) * a0;
            float4 vB = rdf(sB, p);
            fv.x += (vB.x * gaB.x + beB.x) * a1f;
            fv.y += (vB.y * gaB.y + beB.y) * a1f;
            fv.z += (vB.z * gaB.z + beB.z) * a1f;
            fv.w += (vB.w * gaB.w + beB.w) * a1f;
            if (nf > 2) {
                float4 vC = rdf(sC, p);
                fv.x += (vC.x * gaC.x + beC.x) * a2f;
                fv.y += (vC.y * gaC.y + beC.y) * a2f;
                fv.z += (vC.z * gaC.z + beC.z) * a2f;
                fv.w += (vC.w * gaC.w + beC.w) * a2f;
            }
            int cr = lane16 * 4;
            tile[cr + 0][px] = fmaxf(fv.x * ca1.x + cb1.x, fv.x * ca2.x + cb2.x);
            tile[cr + 1][px] = fmaxf(fv.y * ca1.y + cb1.y, fv.y * ca2.y + cb2.y);
            tile[cr + 2][px] = fmaxf(fv.z * ca1.z + cb1.z, fv.z * ca2.z + cb2.z);
            tile[cr + 3][px] = fmaxf(fv.w * ca1.w + cb1.w, fv.w * ca2.w + cb2.w);
        }
    }
    __syncthreads();
#pragma unroll
    for (int wp = 0; wp < 4; wp++) {
        int row = wp * 16 + (tid >> 4);
        int px4 = (tid & 15) * 4;
        int p = pt * 64 + px4;
        if (p < HW) {
            float4 r;
            r.x = tile[row][px4 + 0];
            r.y = tile[row][px4 + 1];
            r.z = tile[row][px4 + 2];
            r.w = tile[row][px4 + 3];
            *(float4*)(out + (size_t)(n * C_ + c0 + row) * HW + p) = r;
        }
    }
}

// --------------------------------------------------------------------- host ----
extern "C" void kernel_launch(void* const* d_in, const int* in_sizes, int n_in,
                              void* d_out, int out_size, void* d_ws, size_t ws_size,
                              hipStream_t stream) {
    (void)in_sizes; (void)n_in; (void)out_size; (void)ws_size;
    const float* x0 = (const float*)d_in[0];
    const float* x1 = (const float*)d_in[1];
    const float* x2 = (const float*)d_in[2];
    const float* dw_w_h = (const float*)d_in[3];
    const float* dw_s_h = (const float*)d_in[4];
    const float* dw_b_h = (const float*)d_in[5];
    const float* dw_w_m = (const float*)d_in[6];
    const float* dw_s_m = (const float*)d_in[7];
    const float* dw_b_m = (const float*)d_in[8];
    const float* dw_w_l = (const float*)d_in[9];
    const float* dw_s_l = (const float*)d_in[10];
    const float* dw_b_l = (const float*)d_in[11];
    const float* off_w = (const float*)d_in[12];
    const float* off_b = (const float*)d_in[13];
    const float* gn_g_h = (const float*)d_in[14];
    const float* gn_b_h = (const float*)d_in[15];
    const float* gn_g_m = (const float*)d_in[16];
    const float* gn_b_m = (const float*)d_in[17];
    const float* gn_g_l = (const float*)d_in[18];
    const float* gn_b_l = (const float*)d_in[19];
    const float* sa_w = (const float*)d_in[20];
    const float* sa_b = (const float*)d_in[21];
    const float* fc1_w = (const float*)d_in[22];
    const float* fc1_b = (const float*)d_in[23];
    const float* fc2_w = (const float*)d_in[24];
    const float* fc2_b = (const float*)d_in[25];

    float* ws = (float*)d_ws;
    unsigned short* XTB0 = (unsigned short*)(ws + 0);        // ws[0 .. 3276800)
    unsigned short* XTB1 = (unsigned short*)(ws + 3276800);  // ws[3276800 .. 4096000)
    unsigned short* XTB2 = (unsigned short*)(ws + 4096000);  // ws[4096000 .. 4300800)
    float* SH = ws + 4300800;      // 6553600 floats
    float* FINA = ws + 10854400;   // 6553600
    float* FINB = ws + 17408000;   // 6553600
    float* FINC = ws + 23961600;   // 1638400
    float* WMF = ws + 25600000;    // 36864
    float* DWT = ws + 25636864;    // 6912
    float* STATS = ws + 25643776;  // 896 (7 slots x 128) — zeroed by k_prep

    unsigned short* SHB = (unsigned short*)SH;
    unsigned short* FINAB = (unsigned short*)FINA;
    unsigned short* WMFB = (unsigned short*)WMF;

    float* out0 = (float*)d_out;
    float* out1 = out0 + 6553600;
    float* out2 = out0 + 8192000;

    // OM scratch carved from not-yet-written outputs: [g][n][pix][28]
    float* OM_l0mid = out0;                 // 2867200
    float* OM_l0high = out0 + 2867200;      // 716800
    float* OM_l1mid = out0 + 3584000;       // 716800
    float* OM_l1low = out0 + 4300800;       // 716800 -> ends 5017600 <= 6553600
    float* OM_l1high = out1;                // 179200
    float* OM_l2mid = out1 + 179200;        // 179200
    float* OM_l2low = out1 + 358400;        // 179200 -> ends 537600 <= 1638400

    // raw sample outputs (bf16), same float-offset bases as before
    unsigned short* RAW_l0mid = (unsigned short*)SH;
    unsigned short* RAW_l0high = (unsigned short*)FINC;
    unsigned short* RAW_l1mid = (unsigned short*)FINB;
    unsigned short* RAW_l1low = (unsigned short*)(FINB + 1638400);
    unsigned short* RAW_l1high = (unsigned short*)(FINB + 3276800);
    unsigned short* RAW_l2mid = (unsigned short*)(FINB + 3686400);
    unsigned short* RAW_l2low = (unsigned short*)(FINB + 4096000);
    // 4x replicated RAWSUM + upsample-weight tables in the free FINB tail
    float* REP = FINB + 4505600;            // 4 x 7168 = 28672 -> ends 4534272
    float* UPW = FINB + 4534272;            // 64 floats (40 for l0high, 20 for l1high)
    // coef/af live in FINA (free after offmask consumed the DWB tiles there)
    float* COEF = FINA;                     // 3 * 4096
    float* AF = FINA + 12288;               // 3 * 16

    const float SYS_L0H = (float)(39.0 / 79.0);
    const float SYS_L1H = (float)(19.0 / 39.0);

    k_prep<<<(4 * 32 * 576 + 6912 + 896 + 28672 + 64 + 255) / 256, 256, 0, stream>>>(
        off_w, dw_w_h, dw_w_m, dw_w_l, WMFB, DWT, STATS, REP, UPW);

    {
        TrP tp{};
        tp.x[0] = x0; tp.xtb[0] = XTB0; tp.H[0] = 80; tp.W[0] = 80; tp.wtc[0] = 3;
        tp.x[1] = x1; tp.xtb[1] = XTB1; tp.H[1] = 40; tp.W[1] = 40; tp.wtc[1] = 2;
        tp.x[2] = x2; tp.xtb[2] = XTB2; tp.H[2] = 20; tp.W[2] = 20; tp.wtc[2] = 1;
        tp.blk[0] = 0; tp.blk[1] = 960; tp.blk[2] = 1280; tp.blk[3] = 1360;
        k_transpose_b<<<dim3(1360, 8), 256, 0, stream>>>(tp);
    }

    // dwb placements (bf16 elem offsets); consumed by offmask
    unsigned short* DWB_x0mid = SHB;                  // 6553600 elems
    unsigned short* DWB_x0low = SHB + 6553600;        // 6553600
    unsigned short* DWB_x1high = FINAB;               // 1638400
    unsigned short* DWB_x1mid = FINAB + 1638400;      // 1638400
    unsigned short* DWB_x1low = FINAB + 3276800;      // 1638400
    unsigned short* DWB_x2high = FINAB + 4915200;     // 409600
    unsigned short* DWB_x2mid = FINAB + 5324800;      // 409600

    {
        DwP dp{};
        dp.xtb[0] = XTB0; dp.out[0] = DWB_x0mid;  dp.wdt[0] = DWT + 1 * 2304;
        dp.sc[0] = dw_s_m; dp.bi[0] = dw_b_m; dp.H[0] = 80; dp.W[0] = 80;
        dp.xtb[1] = XTB0; dp.out[1] = DWB_x0low;  dp.wdt[1] = DWT + 2 * 2304;
        dp.sc[1] = dw_s_l; dp.bi[1] = dw_b_l; dp.H[1] = 80; dp.W[1] = 80;
        dp.xtb[2] = XTB1; dp.out[2] = DWB_x1high; dp.wdt[2] = DWT + 0 * 2304;
        dp.sc[2] = dw_s_h; dp.bi[2] = dw_b_h; dp.H[2] = 40; dp.W[2] = 40;
        dp.xtb[3] = XTB1; dp.out[3] = DWB_x1mid;  dp.wdt[3] = DWT + 1 * 2304;
        dp.sc[3] = dw_s_m; dp.bi[3] = dw_b_m; dp.H[3] = 40; dp.W[3] = 40;
        dp.xtb[4] = XTB1; dp.out[4] = DWB_x1low;  dp.wdt[4] = DWT + 2 * 2304;
        dp.sc[4] = dw_s_l; dp.bi[4] = dw_b_l; dp.H[4] = 40; dp.W[4] = 40;
        dp.xtb[5] = XTB2; dp.out[5] = DWB_x2high; dp.wdt[5] = DWT + 0 * 2304;
        dp.sc[5] = dw_s_h; dp.bi[5] = dw_b_h; dp.H[5] = 20; dp.W[5] = 20;
        dp.xtb[6] = XTB2; dp.out[6] = DWB_x2mid;  dp.wdt[6] = DWT + 1 * 2304;
        dp.sc[6] = dw_s_m; dp.bi[6] = dw_b_m; dp.H[6] = 20; dp.W[6] = 20;
        dp.blk[0] = 0;    dp.blk[1] = 3200; dp.blk[2] = 6400; dp.blk[3] = 7200;
        dp.blk[4] = 8000; dp.blk[5] = 8800; dp.blk[6] = 9000; dp.blk[7] = 9200;
        k_dw_silu_b<<<9200, 256, 0, stream>>>(dp);
    }

    {   // unified offmask: 7 feats, 1 launch
        OmP7 op{};
        auto setf = [&](int i, const unsigned short* dwb, float* om, int Hs, int Ws,
                        int Wo, int HoWo, int ss, int ths, int tws, int SR, int SC,
                        int nz) {
            op.dwb[i] = dwb; op.om[i] = om;
            op.Hs[i] = Hs; op.Ws[i] = Ws; op.Wo[i] = Wo; op.HoWo[i] = HoWo;
            op.ss[i] = ss; op.ths[i] = ths; op.tws[i] = tws;
            op.SR[i] = SR; op.SC[i] = SC; op.Msc[i] = (65536 + SC - 1) / SC;
            op.nz[i] = nz; op.Mnz[i] = (65536 + nz - 1) / nz;
        };
        setf(0, DWB_x0mid,  OM_l0mid,  80, 80, 80, 6400, 0, 3, 3, 10, 10, 10);
        setf(1, DWB_x1high, OM_l0high, 40, 40, 40, 1600, 0, 2, 3, 6,  10, 5);
        setf(2, DWB_x1mid,  OM_l1mid,  40, 40, 40, 1600, 0, 2, 3, 6,  10, 5);
        setf(3, DWB_x0low,  OM_l1low,  80, 80, 40, 1600, 1, 2, 3, 9,  17, 5);
        setf(4, DWB_x2high, OM_l1high, 20, 20, 20, 400,  0, 2, 2, 6,  6,  5);
        setf(5, DWB_x2mid,  OM_l2mid,  20, 20, 20, 400,  0, 2, 2, 6,  6,  5);
        setf(6, DWB_x1low,  OM_l2low,  40, 40, 20, 400,  1, 2, 2, 9,  9,  5);
        op.blk[0] = 0;    op.blk[1] = 1600; op.blk[2] = 2400; op.blk[3] = 3200;
        op.blk[4] = 4000; op.blk[5] = 4400; op.blk[6] = 4800; op.blk[7] = 5200;
        k_offmask_b<<<5200, 256, 0, stream>>>(op, WMFB);
    }

    {
        SmP sp{};
        auto setf = [&](int i, const unsigned short* xtb, const float* om,
                        unsigned short* raw, int slot, int Hs, int Ws, int Wo, int HoWo,
                        int stride, int softmax, int up, const float* upt) {
            sp.xtb[i] = xtb; sp.om[i] = om; sp.raw[i] = raw;
            sp.stats[i] = STATS + slot * 128;
            sp.rsum[i] = REP + slot * 1024;
            sp.upt[i] = upt;
            sp.Hs[i] = Hs; sp.Ws[i] = Ws; sp.Wo[i] = Wo; sp.HoWo[i] = HoWo;
            sp.stride[i] = stride; sp.softmax[i] = softmax; sp.up[i] = up;
        };
        setf(0, XTB0, OM_l0mid,  RAW_l0mid,  0, 80, 80, 80, 6400, 1, 0, 0, UPW);
        setf(1, XTB1, OM_l0high, RAW_l0high, 1, 40, 40, 40, 1600, 1, 1, 1, UPW);
        setf(2, XTB1, OM_l1mid,  RAW_l1mid,  2, 40, 40, 40, 1600, 1, 0, 0, UPW);
        setf(3, XTB0, OM_l1low,  RAW_l1low,  3, 80, 80, 40, 1600, 2, 1, 0, UPW);
        setf(4, XTB2, OM_l1high, RAW_l1high, 4, 20, 20, 20, 400,  1, 1, 1, UPW + 40);
        setf(5, XTB2, OM_l2mid,  RAW_l2mid,  5, 20, 20, 20, 400,  1, 0, 0, UPW);
        setf(6, XTB1, OM_l2low,  RAW_l2low,  6, 40, 40, 20, 400,  2, 1, 0, UPW);
        sp.blk[0] = 0;    sp.blk[1] = 3200; sp.blk[2] = 4000; sp.blk[3] = 4800;
        sp.blk[4] = 5600; sp.blk[5] = 5800; sp.blk[6] = 6000; sp.blk[7] = 6200;
        k_sample_b<<<6200, 256, 0, stream>>>(sp, off_b);
    }

    {
        CfP cp{};
        cp.nf[0] = 2; cp.inv_nl[0] = 0.5f;      cp.inv_hw[0] = 1.f / 6400.f;
        cp.nf[1] = 3; cp.inv_nl[1] = 1.f / 3.f; cp.inv_hw[1] = 1.f / 1600.f;
        cp.nf[2] = 2; cp.inv_nl[2] = 0.5f;      cp.inv_hw[2] = 1.f / 400.f;
        cp.ft[0][0] = {REP + 0 * 1024, STATS + 0 * 128, gn_g_m, gn_b_m, 102400.f};
        cp.ft[0][1] = {REP + 1 * 1024, STATS + 1 * 128, gn_g_h, gn_b_h, 25600.f};
        cp.ft[1][0] = {REP + 2 * 1024, STATS + 2 * 128, gn_g_m, gn_b_m, 25600.f};
        cp.ft[1][1] = {REP + 3 * 1024, STATS + 3 * 128, gn_g_l, gn_b_l, 25600.f};
        cp.ft[1][2] = {REP + 4 * 1024, STATS + 4 * 128, gn_g_h, gn_b_h, 6400.f};
        cp.ft[2][0] = {REP + 5 * 1024, STATS + 5 * 128, gn_g_m, gn_b_m, 6400.f};
        cp.ft[2][1] = {REP + 6 * 1024, STATS + 6 * 128, gn_g_l, gn_b_l, 6400.f};
        k_coef_b<<<12, 256, 0, stream>>>(cp, sa_w, sa_b, fc1_w, fc1_b, fc2_w, fc2_b,
                                         COEF, AF);
    }

    {
        StP st{};
        st.out[0] = out0; st.nf[0] = 2; st.HW[0] = 6400; st.Wf[0] = 80; st.npt[0] = 100;
        st.out[1] = out1; st.nf[1] = 3; st.HW[1] = 1600; st.Wf[1] = 40; st.npt[1] = 25;
        st.out[2] = out2; st.nf[2] = 2; st.HW[2] = 400;  st.Wf[2] = 20; st.npt[2] = 7;
        st.ft[0][0] = {RAW_l0mid,  STATS + 0 * 128, gn_g_m, gn_b_m, 102400.f, 0, 80, 80, 1.f, 1.f};
        st.ft[0][1] = {RAW_l0high, STATS + 1 * 128, gn_g_h, gn_b_h, 25600.f,  1, 40, 40, SYS_L0H, SYS_L0H};
        st.ft[1][0] = {RAW_l1mid,  STATS + 2 * 128, gn_g_m, gn_b_m, 25600.f,  0, 40, 40, 1.f, 1.f};
        st.ft[1][1] = {RAW_l1low,  STATS + 3 * 128, gn_g_l, gn_b_l, 25600.f,  0, 40, 40, 1.f, 1.f};
        st.ft[1][2] = {RAW_l1high, STATS + 4 * 128, gn_g_h, gn_b_h, 6400.f,   1, 20, 20, SYS_L1H, SYS_L1H};
        st.ft[2][0] = {RAW_l2mid,  STATS + 5 * 128, gn_g_m, gn_b_m, 6400.f,   0, 20, 20, 1.f, 1.f};
        st.ft[2][1] = {RAW_l2low,  STATS + 6 * 128, gn_g_l, gn_b_l, 6400.f,   0, 20, 20, 1.f, 1.f};
        st.blk[0] = 0; st.blk[1] = 1600; st.blk[2] = 2000; st.blk[3] = 2112;
        k_store_b<<<2112, 256, 0, stream>>>(st, COEF, AF);
    }
}